// Round 9
// baseline (1903.376 us; speedup 1.0000x reference)
//
#include <hip/hip_runtime.h>

// MeshGNN bf16-MFMA v8. N=50000, E=600000, H=128, L=4.
// R8 change: edge kernel VALU-issue-bound at 36% occupancy (VALU 67%, MFMA
// 10%, VGPR 56). LDS (weight tile) is per-block -> widen blocks at constant
// LDS: edge 512 thr / 256 edges (4 blk x 8 waves = 32 waves/CU = 100% cap),
// fused 512 thr / 128 rows (2 blk x 8 waves = 50% cap). Halves staging and
// barrier overhead per element. Per-wave logic unchanged.

typedef __bf16 bf16x8 __attribute__((ext_vector_type(8)));
typedef float f32x4 __attribute__((ext_vector_type(4)));

__device__ inline ushort f2bf(float f) {
  unsigned u = __builtin_bit_cast(unsigned, f);
  unsigned r = (u + 0x7fff + ((u >> 16) & 1)) >> 16;
  return (ushort)r;
}
__device__ inline float bf2f(ushort h) {
  unsigned u = ((unsigned)h) << 16;
  return __builtin_bit_cast(float, u);
}

// stage bf16 weight [128n][128k] -> LDS [128][136]
template <int NT>
__device__ inline void stage_w(ushort* Ws, const ushort* __restrict__ Wt, int t) {
#pragma unroll
  for (int i = t; i < 2048; i += NT) {
    int r = i >> 4, c = i & 15;
    *(uint4*)&Ws[r * 136 + c * 8] = *(const uint4*)&Wt[r * 128 + c * 8];
  }
}
// acc += A(rows wave*16..+15 in LDS, stride 136) x W(128x128 in LDS)
__device__ inline void mfma_4ks(f32x4* acc, const ushort* A, const ushort* Ws,
                                int wave, int lane) {
  int cl = lane & 15, kq = (lane >> 4) * 8;
  int arow = (wave * 16 + cl) * 136;
#pragma unroll
  for (int ks = 0; ks < 4; ++ks) {
    bf16x8 af = *(const bf16x8*)&A[arow + ks * 32 + kq];
#pragma unroll
    for (int ct = 0; ct < 8; ++ct) {
      bf16x8 bf = *(const bf16x8*)&Ws[(ct * 16 + cl) * 136 + ks * 32 + kq];
      acc[ct] = __builtin_amdgcn_mfma_f32_16x16x32_bf16(af, bf, acc[ct], 0, 0, 0);
    }
  }
}
// acc += A(frags in regs) x W(LDS)
__device__ inline void mfma_regA(f32x4* acc, const bf16x8* af, const ushort* Ws,
                                 int lane) {
  int cl = lane & 15, kq = (lane >> 4) * 8;
#pragma unroll
  for (int ks = 0; ks < 4; ++ks) {
#pragma unroll
    for (int ct = 0; ct < 8; ++ct) {
      bf16x8 bf = *(const bf16x8*)&Ws[(ct * 16 + cl) * 136 + ks * 32 + kq];
      acc[ct] = __builtin_amdgcn_mfma_f32_16x16x32_bf16(af[ks], bf, acc[ct], 0, 0, 0);
    }
  }
}

// ---------------------------------------------------------------------------
// preprocessing: counting sort of edges by dst
__global__ __launch_bounds__(256) void count_int_kernel(const int* __restrict__ dst,
                                                        int* __restrict__ cnti, int E) {
  int e = blockIdx.x * 256 + threadIdx.x;
  if (e < E) atomicAdd(&cnti[dst[e]], 1);
}

// 3-stage multi-block exclusive scan of cnti -> rowptr (+ invf)
__global__ __launch_bounds__(256) void scan_block_sum(const int* __restrict__ cnti,
                                                      int* __restrict__ bsum, int N) {
  int i = blockIdx.x * 256 + threadIdx.x;
  int v = (i < N) ? cnti[i] : 0;
#pragma unroll
  for (int o = 1; o < 64; o <<= 1) v += __shfl_xor(v, o);
  __shared__ int wsum[4];
  if ((threadIdx.x & 63) == 0) wsum[threadIdx.x >> 6] = v;
  __syncthreads();
  if (threadIdx.x == 0) bsum[blockIdx.x] = wsum[0] + wsum[1] + wsum[2] + wsum[3];
}
__global__ __launch_bounds__(256) void scan_partials(int* __restrict__ bsum, int nb) {
  __shared__ int s[256];
  int t = threadIdx.x;
  int v = (t < nb) ? bsum[t] : 0;
  s[t] = v;
  __syncthreads();
  for (int o = 1; o < 256; o <<= 1) {
    int u = (t >= o) ? s[t - o] : 0;
    __syncthreads();
    s[t] += u;
    __syncthreads();
  }
  if (t < nb) bsum[t] = s[t] - v;   // exclusive
}
__global__ __launch_bounds__(256) void scan_final(const int* __restrict__ cnti,
                                                  const int* __restrict__ bsum,
                                                  int* __restrict__ rowptr,
                                                  float* __restrict__ invf, int N) {
  __shared__ int s[256];
  int i = blockIdx.x * 256 + threadIdx.x;
  int t = threadIdx.x;
  int v = (i < N) ? cnti[i] : 0;
  s[t] = v;
  __syncthreads();
  for (int o = 1; o < 256; o <<= 1) {
    int u = (t >= o) ? s[t - o] : 0;
    __syncthreads();
    s[t] += u;
    __syncthreads();
  }
  if (i < N) {
    rowptr[i] = bsum[blockIdx.x] + s[t] - v;
    invf[i] = 1.f / (float)max(v, 1);
  }
}

__global__ __launch_bounds__(256) void scatter_kernel(
    const int* __restrict__ src, const int* __restrict__ dst,
    const float4* __restrict__ ea, const int* __restrict__ rowptr,
    int* __restrict__ tmpc, int* __restrict__ srcs, int* __restrict__ dsts,
    float4* __restrict__ eas, int E) {
  int e = blockIdx.x * 256 + threadIdx.x;
  if (e >= E) return;
  int d = dst[e];
  int r = atomicAdd(&tmpc[d], 1);
  int p = rowptr[d] + r;
  srcs[p] = src[e];
  dsts[p] = d;
  eas[p] = ea[e];
}

// ---------------------------------------------------------------------------
// Weight convert+transpose: Wt[n][k] = bf16(W[k][n]). m==21: lin [128][32] K-pad.
struct WPtrs { const float* src[22]; };
__global__ __launch_bounds__(256) void wconv_kernel(WPtrs p, ushort* __restrict__ wtb,
                                                    ushort* __restrict__ wlin) {
  int m = blockIdx.y;
  int idx = blockIdx.x * 256 + threadIdx.x;
  if (m == 21) {
    if (idx >= 4096) return;
    int n = idx >> 5, k = idx & 31;
    wlin[idx] = (k < 16) ? f2bf(p.src[21][k * 128 + n]) : (ushort)0;
  } else {
    int n = idx >> 7, k = idx & 127;
    wtb[(size_t)m * 16384 + idx] = f2bf(p.src[m][k * 128 + n]);
  }
}

// ---------------------------------------------------------------------------
// lin_hw: h = relu(x@Win+b) ; hwb = bf16(h@Mw1_0 + mb1_0)
__global__ __launch_bounds__(256) void lin_hw_kernel(
    const float* __restrict__ x, const ushort* __restrict__ wlin,
    const float* __restrict__ lb, const ushort* __restrict__ mw1t,
    const float* __restrict__ mb1, float* __restrict__ h,
    ushort* __restrict__ hwb, int N) {
  __shared__ char smem[69632] __attribute__((aligned(16)));
  ushort* xb  = (ushort*)smem;            // [64*32]
  ushort* wsl = (ushort*)(smem + 4096);   // [128*32]
  ushort* As1 = (ushort*)(smem + 12288);  // [64*136]
  ushort* Ws  = (ushort*)(smem + 34816);  // [128*136]
  int t = threadIdx.x, lane = t & 63, wave = t >> 6;
  int m0 = blockIdx.x * 64;
  int cl = lane & 15, kq = (lane >> 4) * 8;

  for (int i = t; i < 2048; i += 256) {
    int row = i >> 5, c = i & 31;
    int m = m0 + row;
    xb[i] = (c < 16 && m < N) ? f2bf(x[(size_t)m * 16 + c]) : (ushort)0;
  }
  for (int i = t; i < 4096 / 8; i += 256)
    *(uint4*)&wsl[i * 8] = *(const uint4*)&wlin[i * 8];
  stage_w<256>(Ws, mw1t, t);
  __syncthreads();

  f32x4 acc[8];
#pragma unroll
  for (int i = 0; i < 8; ++i)
#pragma unroll
    for (int j = 0; j < 4; ++j) acc[i][j] = 0.f;
  {
    bf16x8 af = *(const bf16x8*)&xb[(wave * 16 + cl) * 32 + kq];
#pragma unroll
    for (int ct = 0; ct < 8; ++ct) {
      bf16x8 bf = *(const bf16x8*)&wsl[(ct * 16 + cl) * 32 + kq];
      acc[ct] = __builtin_amdgcn_mfma_f32_16x16x32_bf16(af, bf, acc[ct], 0, 0, 0);
    }
  }
#pragma unroll
  for (int reg = 0; reg < 4; ++reg) {
    int row = wave * 16 + (lane >> 4) * 4 + reg;
    int m = m0 + row;
#pragma unroll
    for (int ct = 0; ct < 8; ++ct) {
      int col = ct * 16 + cl;
      float v = fmaxf(acc[ct][reg] + lb[col], 0.f);
      if (m < N) h[(size_t)m * 128 + col] = v;
      As1[row * 136 + col] = f2bf(v);
    }
  }
  __syncthreads();
  f32x4 acc2[8];
#pragma unroll
  for (int i = 0; i < 8; ++i)
#pragma unroll
    for (int j = 0; j < 4; ++j) acc2[i][j] = 0.f;
  mfma_4ks(acc2, As1, Ws, wave, lane);
#pragma unroll
  for (int reg = 0; reg < 4; ++reg) {
    int m = m0 + wave * 16 + (lane >> 4) * 4 + reg;
    if (m >= N) continue;
#pragma unroll
    for (int ct = 0; ct < 8; ++ct) {
      int col = ct * 16 + cl;
      hwb[(size_t)m * 128 + col] = f2bf(acc2[ct][reg] + mb1[col]);
    }
  }
}

// ---------------------------------------------------------------------------
// edge kernel v7: 512 threads, 256 sorted edges/tile (8 waves x 32 edges);
// A-frags gathered straight into regs, in-register segmented reduction.
__global__ __launch_bounds__(512, 8) void edge_kernel_v7(
    const ushort* __restrict__ hw, const float4* __restrict__ eas,
    const int* __restrict__ srcs, const int* __restrict__ dsts,
    const ushort* __restrict__ W2t, const float* __restrict__ Wea,
    const float* __restrict__ b2, float* __restrict__ agg, int E) {
  __shared__ ushort Ws[128 * 136];   // 34816
  __shared__ float WeaS[4][128];
  __shared__ float b2s[128];
  __shared__ int dss[258];           // [0]=prev-tile, [1..256]=tile, [257]=next
  int t = threadIdx.x, lane = t & 63, wave = t >> 6;
  int cl = lane & 15, g = lane >> 4;
  int p0 = blockIdx.x * 256;
  int base = wave * 32;

  // per-lane gather: lane (cl,g) owns edges base+cl and base+cl+16, k-quarter g
  int e0 = p0 + base + cl, e1 = e0 + 16;
  bool v0 = e0 < E, v1 = e1 < E;
  int s0 = v0 ? srcs[e0] : 0, s1 = v1 ? srcs[e1] : 0;
  float4 ea0 = v0 ? eas[e0] : make_float4(0.f, 0.f, 0.f, 0.f);
  float4 ea1 = v1 ? eas[e1] : make_float4(0.f, 0.f, 0.f, 0.f);
  uint4 hv0[4], hv1[4];
  {
    const ushort* h0 = hw + (size_t)s0 * 128 + g * 8;
    const ushort* h1 = hw + (size_t)s1 * 128 + g * 8;
#pragma unroll
    for (int ks = 0; ks < 4; ++ks) {
      hv0[ks] = *(const uint4*)&h0[ks * 32];
      hv1[ks] = *(const uint4*)&h1[ks * 32];
    }
  }

  // cooperative staging
  stage_w<512>(Ws, W2t, t);
  if (t < 512) { int i = t; if (i < 512) WeaS[i >> 7][i & 127] = Wea[i]; }
  if (t < 128) b2s[t] = b2[t];
  if (t < 256) dss[1 + t] = (p0 + t < E) ? dsts[p0 + t] : -1;
  if (t == 0) dss[0] = (p0 > 0) ? dsts[p0 - 1] : -2;
  if (t == 1) dss[257] = (p0 + 256 < E) ? dsts[p0 + 256] : -3;
  __syncthreads();

  // build A fragments: m1 = relu(hw_src + ea@Wea), rank-4 in fp32
  bf16x8 af0[4], af1[4];
#pragma unroll
  for (int ks = 0; ks < 4; ++ks) {
    union { ushort u16[8]; bf16x8 v; } o0, o1;
    const ushort* q0 = (const ushort*)&hv0[ks];
    const ushort* q1 = (const ushort*)&hv1[ks];
#pragma unroll
    for (int j = 0; j < 8; ++j) {
      int k = ks * 32 + g * 8 + j;
      float w0 = WeaS[0][k], w1 = WeaS[1][k], w2 = WeaS[2][k], w3 = WeaS[3][k];
      float f0 = (v0 ? bf2f(q0[j]) : 0.f) + ea0.x * w0 + ea0.y * w1 + ea0.z * w2 + ea0.w * w3;
      float f1 = (v1 ? bf2f(q1[j]) : 0.f) + ea1.x * w0 + ea1.y * w1 + ea1.z * w2 + ea1.w * w3;
      o0.u16[j] = f2bf(fmaxf(f0, 0.f));
      o1.u16[j] = f2bf(fmaxf(f1, 0.f));
    }
    af0[ks] = o0.v; af1[ks] = o1.v;
  }

  // MFMA
  f32x4 acc0[8], acc1[8];
#pragma unroll
  for (int i = 0; i < 8; ++i)
#pragma unroll
    for (int j = 0; j < 4; ++j) { acc0[i][j] = 0.f; acc1[i][j] = 0.f; }
#pragma unroll
  for (int ks = 0; ks < 4; ++ks) {
#pragma unroll
    for (int ct = 0; ct < 8; ++ct) {
      bf16x8 bf = *(const bf16x8*)&Ws[(ct * 16 + cl) * 136 + ks * 32 + g * 8];
      acc0[ct] = __builtin_amdgcn_mfma_f32_16x16x32_bf16(af0[ks], bf, acc0[ct], 0, 0, 0);
      acc1[ct] = __builtin_amdgcn_mfma_f32_16x16x32_bf16(af1[ks], bf, acc1[ct], 0, 0, 0);
    }
  }

  // m2 = relu(acc + b2) in place  (C layout: row=g*4+reg (+16 for acc1), col=ct*16+cl)
#pragma unroll
  for (int ct = 0; ct < 8; ++ct) {
    float bb = b2s[ct * 16 + cl];
#pragma unroll
    for (int reg = 0; reg < 4; ++reg) {
      acc0[ct][reg] = fmaxf(acc0[ct][reg] + bb, 0.f);
      acc1[ct][reg] = fmaxf(acc1[ct][reg] + bb, 0.f);
    }
  }

  // in-register segmented reduction over dst groups of this wave's 32 rows
  int rloc = lane & 31;
  int dmy = dss[1 + base + rloc];
  int dpv = dss[base + rloc];
  int dafter = dss[1 + base + 32];
  unsigned long long bm = __ballot(dmy != dpv);
  unsigned mask32 = (unsigned)bm | 1u;        // group-start bits in rows 0..31
  bool firstClosed = ((unsigned)bm & 1u) != 0;
  while (mask32) {
    int rOff = __ffs(mask32) - 1;
    unsigned rest = mask32 & (mask32 - 1);
    int eOff = rest ? (__ffs(rest) - 1) : 32;
    mask32 = rest;
    int d = __shfl(dmy, rOff);
    if (d < 0) continue;
    bool openL = (rOff == 0) && !firstClosed;
    bool openR = (eOff == 32) && (dafter == d);
    float ps[8];
#pragma unroll
    for (int ct = 0; ct < 8; ++ct) ps[ct] = 0.f;
#pragma unroll
    for (int reg = 0; reg < 4; ++reg) {
      int r0w = g * 4 + reg;
      bool in0 = (r0w >= rOff) && (r0w < eOff);
      bool in1 = (r0w + 16 >= rOff) && (r0w + 16 < eOff);
#pragma unroll
      for (int ct = 0; ct < 8; ++ct) {
        if (in0) ps[ct] += acc0[ct][reg];
        if (in1) ps[ct] += acc1[ct][reg];
      }
    }
#pragma unroll
    for (int ct = 0; ct < 8; ++ct) {
      ps[ct] += __shfl_xor(ps[ct], 16);
      ps[ct] += __shfl_xor(ps[ct], 32);
    }
    if (g == 0) {
      float* ag = &agg[(size_t)d * 128 + cl];
      if (openL || openR) {
#pragma unroll
        for (int ct = 0; ct < 8; ++ct) atomicAdd(&ag[ct * 16], ps[ct]);
      } else {
#pragma unroll
        for (int ct = 0; ct < 8; ++ct) ag[ct * 16] = ps[ct];
      }
    }
  }
}

// ---------------------------------------------------------------------------
// fused node phase per layer, 512 threads / 128 rows per block:
//   u1 = relu(h@Wu1a + (agg*inv)@Wu1b + b1)   (agg A-frags from global)
//   u  = relu(u1@Wu2 + b2 + h) -> h (skipped on last)
//   l<3 : hwb = bf16(u@Wn + bn) ; l==3: head
__global__ __launch_bounds__(512, 4) void fused_update(
    const float* __restrict__ h, const float* __restrict__ agg,
    const float* __restrict__ inv, const ushort* __restrict__ Wu1a,
    const ushort* __restrict__ Wu1b, const ushort* __restrict__ Wu2,
    const float* __restrict__ b1, const float* __restrict__ b2,
    const ushort* __restrict__ Wn, const float* __restrict__ bn,
    float* __restrict__ h_out, ushort* __restrict__ hwb,
    const float* __restrict__ hw2, const float* __restrict__ hb2,
    float* __restrict__ out, int N, int is_last) {
  __shared__ char smem[69632] __attribute__((aligned(16)));
  ushort* As1 = (ushort*)smem;             // [128*136] = 34816
  ushort* Ws  = (ushort*)(smem + 34816);   // [128*136] = 34816
  float* otile = (float*)smem;             // last: [128*130] = 66560
  float* w2s   = (float*)(smem + 66560);   // last: [384] -> 68096 <= 69632
  int t = threadIdx.x, lane = t & 63, wave = t >> 6;
  int m0 = blockIdx.x * 128;
  int cl = lane & 15, g = lane >> 4;

  // A2 (agg) fragment loads, issued first; land during GEMM1
  int m2r = m0 + wave * 16 + cl;
  bool mv = m2r < N;
  float sI = mv ? inv[m2r] : 0.f;
  float4 ga[8];
  {
    const float* gp = agg + (size_t)(mv ? m2r : 0) * 128 + g * 8;
#pragma unroll
    for (int ks = 0; ks < 4; ++ks) {
      ga[ks * 2 + 0] = *(const float4*)&gp[ks * 32];
      ga[ks * 2 + 1] = *(const float4*)&gp[ks * 32 + 4];
    }
  }

  // stage As1 = bf16(h): thread t -> row t>>2 (0..127), quarter t&3
  {
    int row = t >> 2, q = t & 3;
    int m = m0 + row;
    union { ushort u16[32]; uint4 u4[4]; } a;
    if (m < N) {
      const float* hp = h + (size_t)m * 128 + q * 32;
#pragma unroll
      for (int j = 0; j < 8; ++j) {
        float4 hv = *(const float4*)&hp[j * 4];
        a.u16[j * 4 + 0] = f2bf(hv.x); a.u16[j * 4 + 1] = f2bf(hv.y);
        a.u16[j * 4 + 2] = f2bf(hv.z); a.u16[j * 4 + 3] = f2bf(hv.w);
      }
    } else {
#pragma unroll
      for (int j = 0; j < 32; ++j) a.u16[j] = 0;
    }
#pragma unroll
    for (int j = 0; j < 4; ++j)
      *(uint4*)&As1[row * 136 + q * 32 + j * 8] = a.u4[j];
  }
  stage_w<512>(Ws, Wu1a, t);
  __syncthreads();

  f32x4 acc[8];
#pragma unroll
  for (int i = 0; i < 8; ++i)
#pragma unroll
    for (int j = 0; j < 4; ++j) acc[i][j] = 0.f;
  mfma_4ks(acc, As1, Ws, wave, lane);
  __syncthreads();
  stage_w<512>(Ws, Wu1b, t);
  // build A2 frags (loads have landed): bf16(agg * inv)
  bf16x8 af2[4];
#pragma unroll
  for (int ks = 0; ks < 4; ++ks) {
    union { ushort u16[8]; bf16x8 v; } o;
    const float* f = (const float*)&ga[ks * 2];
#pragma unroll
    for (int j = 0; j < 8; ++j) o.u16[j] = f2bf(f[j] * sI);
    af2[ks] = o.v;
  }
  __syncthreads();
  mfma_regA(acc, af2, Ws, lane);
  __syncthreads();

  // u1 -> As1 bf16 (own C rows)
#pragma unroll
  for (int reg = 0; reg < 4; ++reg) {
    int row = wave * 16 + g * 4 + reg;
#pragma unroll
    for (int ct = 0; ct < 8; ++ct) {
      int col = ct * 16 + cl;
      As1[row * 136 + col] = f2bf(fmaxf(acc[ct][reg] + b1[col], 0.f));
    }
  }
  stage_w<512>(Ws, Wu2, t);
  __syncthreads();

  f32x4 acc2[8];
#pragma unroll
  for (int i = 0; i < 8; ++i)
#pragma unroll
    for (int j = 0; j < 4; ++j) acc2[i][j] = 0.f;
  mfma_4ks(acc2, As1, Ws, wave, lane);
  __syncthreads();

  // u = relu(acc2 + b2 + h) -> h_out + As1 bf16
#pragma unroll
  for (int reg = 0; reg < 4; ++reg) {
    int row = wave * 16 + g * 4 + reg;
    int m = m0 + row;
#pragma unroll
    for (int ct = 0; ct < 8; ++ct) {
      int col = ct * 16 + cl;
      float v = acc2[ct][reg] + b2[col];
      if (m < N) v += h[(size_t)m * 128 + col];
      v = fmaxf(v, 0.f);
      if (!is_last && m < N) h_out[(size_t)m * 128 + col] = v;
      As1[row * 136 + col] = f2bf(v);
    }
  }
  stage_w<512>(Ws, Wn, t);
  __syncthreads();

  f32x4 acc3[8];
#pragma unroll
  for (int i = 0; i < 8; ++i)
#pragma unroll
    for (int j = 0; j < 4; ++j) acc3[i][j] = 0.f;
  mfma_4ks(acc3, As1, Ws, wave, lane);

  if (!is_last) {
#pragma unroll
    for (int reg = 0; reg < 4; ++reg) {
      int m = m0 + wave * 16 + g * 4 + reg;
      if (m >= N) continue;
#pragma unroll
      for (int ct = 0; ct < 8; ++ct) {
        int col = ct * 16 + cl;
        hwb[(size_t)m * 128 + col] = f2bf(acc3[ct][reg] + bn[col]);
      }
    }
  } else {
    __syncthreads();
#pragma unroll
    for (int reg = 0; reg < 4; ++reg) {
      int row = wave * 16 + g * 4 + reg;
#pragma unroll
      for (int ct = 0; ct < 8; ++ct) {
        int col = ct * 16 + cl;
        otile[row * 130 + col] = fmaxf(acc3[ct][reg] + bn[col], 0.f);
      }
    }
    for (int i = t; i < 384; i += 512) w2s[i] = hw2[i];
    __syncthreads();
    if (t < 384) {
      int row = t / 3, c = t % 3;
      int m = m0 + row;
      if (m < N) {
        float s = hb2[c];
#pragma unroll 16
        for (int k = 0; k < 128; ++k) s += otile[row * 130 + k] * w2s[k * 3 + c];
        out[(size_t)m * 3 + c] = fmaxf(s, 0.f);
      }
    }
  }
}

// ---------------------------------------------------------------------------
extern "C" void kernel_launch(void* const* d_in, const int* in_sizes, int n_in,
                              void* d_out, int out_size, void* d_ws, size_t ws_size,
                              hipStream_t stream) {
  const float* x       = (const float*)d_in[0];
  const int*   ei      = (const int*)  d_in[1];
  const float* ea      = (const float*)d_in[2];
  const float* lin_w   = (const float*)d_in[3];
  const float* lin_b   = (const float*)d_in[4];
  const float* msg_w1  = (const float*)d_in[5];
  const float* msg_b1  = (const float*)d_in[6];
  const float* msg_w2  = (const float*)d_in[7];
  const float* msg_b2  = (const float*)d_in[8];
  const float* upd_w1  = (const float*)d_in[9];
  const float* upd_b1  = (const float*)d_in[10];
  const float* upd_w2  = (const float*)d_in[11];
  const float* upd_b2  = (const float*)d_in[12];
  const float* head_w1 = (const float*)d_in[13];
  const float* head_b1 = (const float*)d_in[14];
  const float* head_w2 = (const float*)d_in[15];
  const float* head_b2 = (const float*)d_in[16];

  int N = in_sizes[0] / 16;
  int E = in_sizes[1] / 2;
  const int* src = ei;
  const int* dst = ei + E;

  float* ws = (float*)d_ws;
  size_t NH = (size_t)N * 128;
  size_t Nr = ((size_t)N + 4) & ~(size_t)3;
  size_t Er = ((size_t)E + 3) & ~(size_t)3;
  size_t off = 0;
  float*  h    = ws + off; off += NH;
  float*  agg  = ws + off; off += NH;
  float4* eas  = (float4*)(ws + off); off += 4 * Er;
  float*  invf = ws + off; off += Nr;
  ushort* wtb  = (ushort*)(ws + off); off += (size_t)21 * 16384 / 2;
  ushort* wlin = (ushort*)(ws + off); off += 4096 / 2;
  ushort* hwb  = (ushort*)(ws + off); off += NH / 2;
  int*    cnti = (int*)(ws + off); off += Nr;
  int*    tmpc = (int*)(ws + off); off += Nr;
  int*    rowp = (int*)(ws + off); off += Nr;
  int*    srcs = (int*)(ws + off); off += Er;
  int*    dsts = (int*)(ws + off); off += Er;
  int*    bsum = (int*)(ws + off); off += 256;
  float*  out  = (float*)d_out;

  WPtrs wp;
  for (int l = 0; l < 4; ++l) {
    wp.src[l * 5 + 0] = msg_w1 + (size_t)l * 132 * 128;
    wp.src[l * 5 + 1] = msg_w2 + (size_t)l * 128 * 128;
    wp.src[l * 5 + 2] = upd_w1 + (size_t)l * 256 * 128;
    wp.src[l * 5 + 3] = upd_w1 + (size_t)l * 256 * 128 + 128 * 128;
    wp.src[l * 5 + 4] = upd_w2 + (size_t)l * 128 * 128;
  }
  wp.src[20] = head_w1;
  wp.src[21] = lin_w;

  int ngrid = (N + 63) / 64;
  int fgrid = (N + 127) / 128;
  int egrid = (E + 255) / 256;
  int nscan = (N + 255) / 256;   // 196 <= 256 partials

  hipMemsetAsync(cnti, 0, Nr * 4, stream);
  hipMemsetAsync(tmpc, 0, Nr * 4, stream);
  wconv_kernel<<<dim3(64, 22), 256, 0, stream>>>(wp, wtb, wlin);
  count_int_kernel<<<(E + 255) / 256, 256, 0, stream>>>(dst, cnti, E);
  scan_block_sum<<<nscan, 256, 0, stream>>>(cnti, bsum, N);
  scan_partials<<<1, 256, 0, stream>>>(bsum, nscan);
  scan_final<<<nscan, 256, 0, stream>>>(cnti, bsum, rowp, invf, N);
  scatter_kernel<<<(E + 255) / 256, 256, 0, stream>>>(src, dst, (const float4*)ea,
                                                      rowp, tmpc, srcs, dsts, eas, E);
  lin_hw_kernel<<<ngrid, 256, 0, stream>>>(x, wlin, lin_b, wtb, msg_b1, h, hwb, N);

  for (int l = 0; l < 4; ++l) {
    const ushort* mw2t  = wtb + (size_t)(l * 5 + 1) * 16384;
    const ushort* wu1at = wtb + (size_t)(l * 5 + 2) * 16384;
    const ushort* wu1bt = wtb + (size_t)(l * 5 + 3) * 16384;
    const ushort* wu2t  = wtb + (size_t)(l * 5 + 4) * 16384;
    const float*  wea   = msg_w1 + (size_t)l * 132 * 128 + 128 * 128;
    int last = (l == 3);
    const ushort* Wn = last ? (wtb + (size_t)20 * 16384)
                            : (wtb + (size_t)((l + 1) * 5 + 0) * 16384);
    const float* bn = last ? head_b1 : (msg_b1 + (l + 1) * 128);

    hipMemsetAsync(agg, 0, NH * sizeof(float), stream);
    edge_kernel_v7<<<egrid, 512, 0, stream>>>(hwb, eas, srcs, dsts, mw2t, wea,
                                              msg_b2 + l * 128, agg, E);
    fused_update<<<fgrid, 512, 0, stream>>>(h, agg, invf, wu1at, wu1bt, wu2t,
                                            upd_b1 + l * 128, upd_b2 + l * 128,
                                            Wn, bn, h, last ? nullptr : hwb,
                                            head_w2, head_b2, out, N, last);
  }
}

// Round 10
// 648.358 us; speedup vs baseline: 2.9357x; 2.9357x over previous
//
#include <hip/hip_runtime.h>

// MeshGNN bf16-MFMA v9. N=50000, E=600000, H=128, L=4.
// R9 fix: R8's __launch_bounds__(512, 8) capped VGPR at 64 -> spilled ~100
// VGPRs to scratch (VGPR_Count=32, FETCH 682MB, WRITE 847MB = scratch traffic,
// 405us). Same kernel with (512, 4): VGPR cap 128, kernel wants ~60 ->
// LDS-limited 4 blocks x 8 waves = 32 waves/CU cap, no spills.

typedef __bf16 bf16x8 __attribute__((ext_vector_type(8)));
typedef float f32x4 __attribute__((ext_vector_type(4)));

__device__ inline ushort f2bf(float f) {
  unsigned u = __builtin_bit_cast(unsigned, f);
  unsigned r = (u + 0x7fff + ((u >> 16) & 1)) >> 16;
  return (ushort)r;
}
__device__ inline float bf2f(ushort h) {
  unsigned u = ((unsigned)h) << 16;
  return __builtin_bit_cast(float, u);
}

// stage bf16 weight [128n][128k] -> LDS [128][136]
template <int NT>
__device__ inline void stage_w(ushort* Ws, const ushort* __restrict__ Wt, int t) {
#pragma unroll
  for (int i = t; i < 2048; i += NT) {
    int r = i >> 4, c = i & 15;
    *(uint4*)&Ws[r * 136 + c * 8] = *(const uint4*)&Wt[r * 128 + c * 8];
  }
}
// acc += A(rows wave*16..+15 in LDS, stride 136) x W(128x128 in LDS)
__device__ inline void mfma_4ks(f32x4* acc, const ushort* A, const ushort* Ws,
                                int wave, int lane) {
  int cl = lane & 15, kq = (lane >> 4) * 8;
  int arow = (wave * 16 + cl) * 136;
#pragma unroll
  for (int ks = 0; ks < 4; ++ks) {
    bf16x8 af = *(const bf16x8*)&A[arow + ks * 32 + kq];
#pragma unroll
    for (int ct = 0; ct < 8; ++ct) {
      bf16x8 bf = *(const bf16x8*)&Ws[(ct * 16 + cl) * 136 + ks * 32 + kq];
      acc[ct] = __builtin_amdgcn_mfma_f32_16x16x32_bf16(af, bf, acc[ct], 0, 0, 0);
    }
  }
}
// acc += A(frags in regs) x W(LDS)
__device__ inline void mfma_regA(f32x4* acc, const bf16x8* af, const ushort* Ws,
                                 int lane) {
  int cl = lane & 15, kq = (lane >> 4) * 8;
#pragma unroll
  for (int ks = 0; ks < 4; ++ks) {
#pragma unroll
    for (int ct = 0; ct < 8; ++ct) {
      bf16x8 bf = *(const bf16x8*)&Ws[(ct * 16 + cl) * 136 + ks * 32 + kq];
      acc[ct] = __builtin_amdgcn_mfma_f32_16x16x32_bf16(af[ks], bf, acc[ct], 0, 0, 0);
    }
  }
}

// ---------------------------------------------------------------------------
// preprocessing: counting sort of edges by dst
__global__ __launch_bounds__(256) void count_int_kernel(const int* __restrict__ dst,
                                                        int* __restrict__ cnti, int E) {
  int e = blockIdx.x * 256 + threadIdx.x;
  if (e < E) atomicAdd(&cnti[dst[e]], 1);
}

// 3-stage multi-block exclusive scan of cnti -> rowptr (+ invf)
__global__ __launch_bounds__(256) void scan_block_sum(const int* __restrict__ cnti,
                                                      int* __restrict__ bsum, int N) {
  int i = blockIdx.x * 256 + threadIdx.x;
  int v = (i < N) ? cnti[i] : 0;
#pragma unroll
  for (int o = 1; o < 64; o <<= 1) v += __shfl_xor(v, o);
  __shared__ int wsum[4];
  if ((threadIdx.x & 63) == 0) wsum[threadIdx.x >> 6] = v;
  __syncthreads();
  if (threadIdx.x == 0) bsum[blockIdx.x] = wsum[0] + wsum[1] + wsum[2] + wsum[3];
}
__global__ __launch_bounds__(256) void scan_partials(int* __restrict__ bsum, int nb) {
  __shared__ int s[256];
  int t = threadIdx.x;
  int v = (t < nb) ? bsum[t] : 0;
  s[t] = v;
  __syncthreads();
  for (int o = 1; o < 256; o <<= 1) {
    int u = (t >= o) ? s[t - o] : 0;
    __syncthreads();
    s[t] += u;
    __syncthreads();
  }
  if (t < nb) bsum[t] = s[t] - v;   // exclusive
}
__global__ __launch_bounds__(256) void scan_final(const int* __restrict__ cnti,
                                                  const int* __restrict__ bsum,
                                                  int* __restrict__ rowptr,
                                                  float* __restrict__ invf, int N) {
  __shared__ int s[256];
  int i = blockIdx.x * 256 + threadIdx.x;
  int t = threadIdx.x;
  int v = (i < N) ? cnti[i] : 0;
  s[t] = v;
  __syncthreads();
  for (int o = 1; o < 256; o <<= 1) {
    int u = (t >= o) ? s[t - o] : 0;
    __syncthreads();
    s[t] += u;
    __syncthreads();
  }
  if (i < N) {
    rowptr[i] = bsum[blockIdx.x] + s[t] - v;
    invf[i] = 1.f / (float)max(v, 1);
  }
}

__global__ __launch_bounds__(256) void scatter_kernel(
    const int* __restrict__ src, const int* __restrict__ dst,
    const float4* __restrict__ ea, const int* __restrict__ rowptr,
    int* __restrict__ tmpc, int* __restrict__ srcs, int* __restrict__ dsts,
    float4* __restrict__ eas, int E) {
  int e = blockIdx.x * 256 + threadIdx.x;
  if (e >= E) return;
  int d = dst[e];
  int r = atomicAdd(&tmpc[d], 1);
  int p = rowptr[d] + r;
  srcs[p] = src[e];
  dsts[p] = d;
  eas[p] = ea[e];
}

// ---------------------------------------------------------------------------
// Weight convert+transpose: Wt[n][k] = bf16(W[k][n]). m==21: lin [128][32] K-pad.
struct WPtrs { const float* src[22]; };
__global__ __launch_bounds__(256) void wconv_kernel(WPtrs p, ushort* __restrict__ wtb,
                                                    ushort* __restrict__ wlin) {
  int m = blockIdx.y;
  int idx = blockIdx.x * 256 + threadIdx.x;
  if (m == 21) {
    if (idx >= 4096) return;
    int n = idx >> 5, k = idx & 31;
    wlin[idx] = (k < 16) ? f2bf(p.src[21][k * 128 + n]) : (ushort)0;
  } else {
    int n = idx >> 7, k = idx & 127;
    wtb[(size_t)m * 16384 + idx] = f2bf(p.src[m][k * 128 + n]);
  }
}

// ---------------------------------------------------------------------------
// lin_hw: h = relu(x@Win+b) ; hwb = bf16(h@Mw1_0 + mb1_0)
__global__ __launch_bounds__(256) void lin_hw_kernel(
    const float* __restrict__ x, const ushort* __restrict__ wlin,
    const float* __restrict__ lb, const ushort* __restrict__ mw1t,
    const float* __restrict__ mb1, float* __restrict__ h,
    ushort* __restrict__ hwb, int N) {
  __shared__ char smem[69632] __attribute__((aligned(16)));
  ushort* xb  = (ushort*)smem;            // [64*32]
  ushort* wsl = (ushort*)(smem + 4096);   // [128*32]
  ushort* As1 = (ushort*)(smem + 12288);  // [64*136]
  ushort* Ws  = (ushort*)(smem + 34816);  // [128*136]
  int t = threadIdx.x, lane = t & 63, wave = t >> 6;
  int m0 = blockIdx.x * 64;
  int cl = lane & 15, kq = (lane >> 4) * 8;

  for (int i = t; i < 2048; i += 256) {
    int row = i >> 5, c = i & 31;
    int m = m0 + row;
    xb[i] = (c < 16 && m < N) ? f2bf(x[(size_t)m * 16 + c]) : (ushort)0;
  }
  for (int i = t; i < 4096 / 8; i += 256)
    *(uint4*)&wsl[i * 8] = *(const uint4*)&wlin[i * 8];
  stage_w<256>(Ws, mw1t, t);
  __syncthreads();

  f32x4 acc[8];
#pragma unroll
  for (int i = 0; i < 8; ++i)
#pragma unroll
    for (int j = 0; j < 4; ++j) acc[i][j] = 0.f;
  {
    bf16x8 af = *(const bf16x8*)&xb[(wave * 16 + cl) * 32 + kq];
#pragma unroll
    for (int ct = 0; ct < 8; ++ct) {
      bf16x8 bf = *(const bf16x8*)&wsl[(ct * 16 + cl) * 32 + kq];
      acc[ct] = __builtin_amdgcn_mfma_f32_16x16x32_bf16(af, bf, acc[ct], 0, 0, 0);
    }
  }
#pragma unroll
  for (int reg = 0; reg < 4; ++reg) {
    int row = wave * 16 + (lane >> 4) * 4 + reg;
    int m = m0 + row;
#pragma unroll
    for (int ct = 0; ct < 8; ++ct) {
      int col = ct * 16 + cl;
      float v = fmaxf(acc[ct][reg] + lb[col], 0.f);
      if (m < N) h[(size_t)m * 128 + col] = v;
      As1[row * 136 + col] = f2bf(v);
    }
  }
  __syncthreads();
  f32x4 acc2[8];
#pragma unroll
  for (int i = 0; i < 8; ++i)
#pragma unroll
    for (int j = 0; j < 4; ++j) acc2[i][j] = 0.f;
  mfma_4ks(acc2, As1, Ws, wave, lane);
#pragma unroll
  for (int reg = 0; reg < 4; ++reg) {
    int m = m0 + wave * 16 + (lane >> 4) * 4 + reg;
    if (m >= N) continue;
#pragma unroll
    for (int ct = 0; ct < 8; ++ct) {
      int col = ct * 16 + cl;
      hwb[(size_t)m * 128 + col] = f2bf(acc2[ct][reg] + mb1[col]);
    }
  }
}

// ---------------------------------------------------------------------------
// edge kernel v7: 512 threads, 256 sorted edges/tile (8 waves x 32 edges);
// A-frags gathered straight into regs, in-register segmented reduction.
// __launch_bounds__(512, 4): VGPR cap 128 (kernel wants ~60); occupancy is
// LDS-limited at 4 blocks/CU = 32 waves.
__global__ __launch_bounds__(512, 4) void edge_kernel_v7(
    const ushort* __restrict__ hw, const float4* __restrict__ eas,
    const int* __restrict__ srcs, const int* __restrict__ dsts,
    const ushort* __restrict__ W2t, const float* __restrict__ Wea,
    const float* __restrict__ b2, float* __restrict__ agg, int E) {
  __shared__ ushort Ws[128 * 136];   // 34816
  __shared__ float WeaS[4][128];
  __shared__ float b2s[128];
  __shared__ int dss[258];           // [0]=prev-tile, [1..256]=tile, [257]=next
  int t = threadIdx.x, lane = t & 63, wave = t >> 6;
  int cl = lane & 15, g = lane >> 4;
  int p0 = blockIdx.x * 256;
  int base = wave * 32;

  // per-lane gather: lane (cl,g) owns edges base+cl and base+cl+16, k-quarter g
  int e0 = p0 + base + cl, e1 = e0 + 16;
  bool v0 = e0 < E, v1 = e1 < E;
  int s0 = v0 ? srcs[e0] : 0, s1 = v1 ? srcs[e1] : 0;
  float4 ea0 = v0 ? eas[e0] : make_float4(0.f, 0.f, 0.f, 0.f);
  float4 ea1 = v1 ? eas[e1] : make_float4(0.f, 0.f, 0.f, 0.f);
  uint4 hv0[4], hv1[4];
  {
    const ushort* h0 = hw + (size_t)s0 * 128 + g * 8;
    const ushort* h1 = hw + (size_t)s1 * 128 + g * 8;
#pragma unroll
    for (int ks = 0; ks < 4; ++ks) {
      hv0[ks] = *(const uint4*)&h0[ks * 32];
      hv1[ks] = *(const uint4*)&h1[ks * 32];
    }
  }

  // cooperative staging
  stage_w<512>(Ws, W2t, t);
  if (t < 512) WeaS[t >> 7][t & 127] = Wea[t];
  if (t < 128) b2s[t] = b2[t];
  if (t < 256) dss[1 + t] = (p0 + t < E) ? dsts[p0 + t] : -1;
  if (t == 0) dss[0] = (p0 > 0) ? dsts[p0 - 1] : -2;
  if (t == 1) dss[257] = (p0 + 256 < E) ? dsts[p0 + 256] : -3;
  __syncthreads();

  // build A fragments: m1 = relu(hw_src + ea@Wea), rank-4 in fp32
  bf16x8 af0[4], af1[4];
#pragma unroll
  for (int ks = 0; ks < 4; ++ks) {
    union { ushort u16[8]; bf16x8 v; } o0, o1;
    const ushort* q0 = (const ushort*)&hv0[ks];
    const ushort* q1 = (const ushort*)&hv1[ks];
#pragma unroll
    for (int j = 0; j < 8; ++j) {
      int k = ks * 32 + g * 8 + j;
      float w0 = WeaS[0][k], w1 = WeaS[1][k], w2 = WeaS[2][k], w3 = WeaS[3][k];
      float f0 = (v0 ? bf2f(q0[j]) : 0.f) + ea0.x * w0 + ea0.y * w1 + ea0.z * w2 + ea0.w * w3;
      float f1 = (v1 ? bf2f(q1[j]) : 0.f) + ea1.x * w0 + ea1.y * w1 + ea1.z * w2 + ea1.w * w3;
      o0.u16[j] = f2bf(fmaxf(f0, 0.f));
      o1.u16[j] = f2bf(fmaxf(f1, 0.f));
    }
    af0[ks] = o0.v; af1[ks] = o1.v;
  }

  // MFMA
  f32x4 acc0[8], acc1[8];
#pragma unroll
  for (int i = 0; i < 8; ++i)
#pragma unroll
    for (int j = 0; j < 4; ++j) { acc0[i][j] = 0.f; acc1[i][j] = 0.f; }
#pragma unroll
  for (int ks = 0; ks < 4; ++ks) {
#pragma unroll
    for (int ct = 0; ct < 8; ++ct) {
      bf16x8 bf = *(const bf16x8*)&Ws[(ct * 16 + cl) * 136 + ks * 32 + g * 8];
      acc0[ct] = __builtin_amdgcn_mfma_f32_16x16x32_bf16(af0[ks], bf, acc0[ct], 0, 0, 0);
      acc1[ct] = __builtin_amdgcn_mfma_f32_16x16x32_bf16(af1[ks], bf, acc1[ct], 0, 0, 0);
    }
  }

  // m2 = relu(acc + b2) in place  (C layout: row=g*4+reg (+16 for acc1), col=ct*16+cl)
#pragma unroll
  for (int ct = 0; ct < 8; ++ct) {
    float bb = b2s[ct * 16 + cl];
#pragma unroll
    for (int reg = 0; reg < 4; ++reg) {
      acc0[ct][reg] = fmaxf(acc0[ct][reg] + bb, 0.f);
      acc1[ct][reg] = fmaxf(acc1[ct][reg] + bb, 0.f);
    }
  }

  // in-register segmented reduction over dst groups of this wave's 32 rows
  int rloc = lane & 31;
  int dmy = dss[1 + base + rloc];
  int dpv = dss[base + rloc];
  int dafter = dss[1 + base + 32];
  unsigned long long bm = __ballot(dmy != dpv);
  unsigned mask32 = (unsigned)bm | 1u;        // group-start bits in rows 0..31
  bool firstClosed = ((unsigned)bm & 1u) != 0;
  while (mask32) {
    int rOff = __ffs(mask32) - 1;
    unsigned rest = mask32 & (mask32 - 1);
    int eOff = rest ? (__ffs(rest) - 1) : 32;
    mask32 = rest;
    int d = __shfl(dmy, rOff);
    if (d < 0) continue;
    bool openL = (rOff == 0) && !firstClosed;
    bool openR = (eOff == 32) && (dafter == d);
    float ps[8];
#pragma unroll
    for (int ct = 0; ct < 8; ++ct) ps[ct] = 0.f;
#pragma unroll
    for (int reg = 0; reg < 4; ++reg) {
      int r0w = g * 4 + reg;
      bool in0 = (r0w >= rOff) && (r0w < eOff);
      bool in1 = (r0w + 16 >= rOff) && (r0w + 16 < eOff);
#pragma unroll
      for (int ct = 0; ct < 8; ++ct) {
        if (in0) ps[ct] += acc0[ct][reg];
        if (in1) ps[ct] += acc1[ct][reg];
      }
    }
#pragma unroll
    for (int ct = 0; ct < 8; ++ct) {
      ps[ct] += __shfl_xor(ps[ct], 16);
      ps[ct] += __shfl_xor(ps[ct], 32);
    }
    if (g == 0) {
      float* ag = &agg[(size_t)d * 128 + cl];
      if (openL || openR) {
#pragma unroll
        for (int ct = 0; ct < 8; ++ct) atomicAdd(&ag[ct * 16], ps[ct]);
      } else {
#pragma unroll
        for (int ct = 0; ct < 8; ++ct) ag[ct * 16] = ps[ct];
      }
    }
  }
}

// ---------------------------------------------------------------------------
// fused node phase per layer, 512 threads / 128 rows per block:
//   u1 = relu(h@Wu1a + (agg*inv)@Wu1b + b1)   (agg A-frags from global)
//   u  = relu(u1@Wu2 + b2 + h) -> h (skipped on last)
//   l<3 : hwb = bf16(u@Wn + bn) ; l==3: head
__global__ __launch_bounds__(512, 2) void fused_update(
    const float* __restrict__ h, const float* __restrict__ agg,
    const float* __restrict__ inv, const ushort* __restrict__ Wu1a,
    const ushort* __restrict__ Wu1b, const ushort* __restrict__ Wu2,
    const float* __restrict__ b1, const float* __restrict__ b2,
    const ushort* __restrict__ Wn, const float* __restrict__ bn,
    float* __restrict__ h_out, ushort* __restrict__ hwb,
    const float* __restrict__ hw2, const float* __restrict__ hb2,
    float* __restrict__ out, int N, int is_last) {
  __shared__ char smem[69632] __attribute__((aligned(16)));
  ushort* As1 = (ushort*)smem;             // [128*136] = 34816
  ushort* Ws  = (ushort*)(smem + 34816);   // [128*136] = 34816
  float* otile = (float*)smem;             // last: [128*130] = 66560
  float* w2s   = (float*)(smem + 66560);   // last: [384] -> 68096 <= 69632
  int t = threadIdx.x, lane = t & 63, wave = t >> 6;
  int m0 = blockIdx.x * 128;
  int cl = lane & 15, g = lane >> 4;

  // A2 (agg) fragment loads, issued first; land during GEMM1
  int m2r = m0 + wave * 16 + cl;
  bool mv = m2r < N;
  float sI = mv ? inv[m2r] : 0.f;
  float4 ga[8];
  {
    const float* gp = agg + (size_t)(mv ? m2r : 0) * 128 + g * 8;
#pragma unroll
    for (int ks = 0; ks < 4; ++ks) {
      ga[ks * 2 + 0] = *(const float4*)&gp[ks * 32];
      ga[ks * 2 + 1] = *(const float4*)&gp[ks * 32 + 4];
    }
  }

  // stage As1 = bf16(h): thread t -> row t>>2 (0..127), quarter t&3
  {
    int row = t >> 2, q = t & 3;
    int m = m0 + row;
    union { ushort u16[32]; uint4 u4[4]; } a;
    if (m < N) {
      const float* hp = h + (size_t)m * 128 + q * 32;
#pragma unroll
      for (int j = 0; j < 8; ++j) {
        float4 hv = *(const float4*)&hp[j * 4];
        a.u16[j * 4 + 0] = f2bf(hv.x); a.u16[j * 4 + 1] = f2bf(hv.y);
        a.u16[j * 4 + 2] = f2bf(hv.z); a.u16[j * 4 + 3] = f2bf(hv.w);
      }
    } else {
#pragma unroll
      for (int j = 0; j < 32; ++j) a.u16[j] = 0;
    }
#pragma unroll
    for (int j = 0; j < 4; ++j)
      *(uint4*)&As1[row * 136 + q * 32 + j * 8] = a.u4[j];
  }
  stage_w<512>(Ws, Wu1a, t);
  __syncthreads();

  f32x4 acc[8];
#pragma unroll
  for (int i = 0; i < 8; ++i)
#pragma unroll
    for (int j = 0; j < 4; ++j) acc[i][j] = 0.f;
  mfma_4ks(acc, As1, Ws, wave, lane);
  __syncthreads();
  stage_w<512>(Ws, Wu1b, t);
  // build A2 frags (loads have landed): bf16(agg * inv)
  bf16x8 af2[4];
#pragma unroll
  for (int ks = 0; ks < 4; ++ks) {
    union { ushort u16[8]; bf16x8 v; } o;
    const float* f = (const float*)&ga[ks * 2];
#pragma unroll
    for (int j = 0; j < 8; ++j) o.u16[j] = f2bf(f[j] * sI);
    af2[ks] = o.v;
  }
  __syncthreads();
  mfma_regA(acc, af2, Ws, lane);
  __syncthreads();

  // u1 -> As1 bf16 (own C rows)
#pragma unroll
  for (int reg = 0; reg < 4; ++reg) {
    int row = wave * 16 + g * 4 + reg;
#pragma unroll
    for (int ct = 0; ct < 8; ++ct) {
      int col = ct * 16 + cl;
      As1[row * 136 + col] = f2bf(fmaxf(acc[ct][reg] + b1[col], 0.f));
    }
  }
  stage_w<512>(Ws, Wu2, t);
  __syncthreads();

  f32x4 acc2[8];
#pragma unroll
  for (int i = 0; i < 8; ++i)
#pragma unroll
    for (int j = 0; j < 4; ++j) acc2[i][j] = 0.f;
  mfma_4ks(acc2, As1, Ws, wave, lane);
  __syncthreads();

  // u = relu(acc2 + b2 + h) -> h_out + As1 bf16
#pragma unroll
  for (int reg = 0; reg < 4; ++reg) {
    int row = wave * 16 + g * 4 + reg;
    int m = m0 + row;
#pragma unroll
    for (int ct = 0; ct < 8; ++ct) {
      int col = ct * 16 + cl;
      float v = acc2[ct][reg] + b2[col];
      if (m < N) v += h[(size_t)m * 128 + col];
      v = fmaxf(v, 0.f);
      if (!is_last && m < N) h_out[(size_t)m * 128 + col] = v;
      As1[row * 136 + col] = f2bf(v);
    }
  }
  stage_w<512>(Ws, Wn, t);
  __syncthreads();

  f32x4 acc3[8];
#pragma unroll
  for (int i = 0; i < 8; ++i)
#pragma unroll
    for (int j = 0; j < 4; ++j) acc3[i][j] = 0.f;
  mfma_4ks(acc3, As1, Ws, wave, lane);

  if (!is_last) {
#pragma unroll
    for (int reg = 0; reg < 4; ++reg) {
      int m = m0 + wave * 16 + g * 4 + reg;
      if (m >= N) continue;
#pragma unroll
      for (int ct = 0; ct < 8; ++ct) {
        int col = ct * 16 + cl;
        hwb[(size_t)m * 128 + col] = f2bf(acc3[ct][reg] + bn[col]);
      }
    }
  } else {
    __syncthreads();
#pragma unroll
    for (int reg = 0; reg < 4; ++reg) {
      int row = wave * 16 + g * 4 + reg;
#pragma unroll
      for (int ct = 0; ct < 8; ++ct) {
        int col = ct * 16 + cl;
        otile[row * 130 + col] = fmaxf(acc3[ct][reg] + bn[col], 0.f);
      }
    }
    for (int i = t; i < 384; i += 512) w2s[i] = hw2[i];
    __syncthreads();
    if (t < 384) {
      int row = t / 3, c = t % 3;
      int m = m0 + row;
      if (m < N) {
        float s = hb2[c];
#pragma unroll 16
        for (int k = 0; k < 128; ++k) s += otile[row * 130 + k] * w2s[k * 3 + c];
        out[(size_t)m * 3 + c] = fmaxf(s, 0.f);
      }
    }
  }
}

// ---------------------------------------------------------------------------
extern "C" void kernel_launch(void* const* d_in, const int* in_sizes, int n_in,
                              void* d_out, int out_size, void* d_ws, size_t ws_size,
                              hipStream_t stream) {
  const float* x       = (const float*)d_in[0];
  const int*   ei      = (const int*)  d_in[1];
  const float* ea      = (const float*)d_in[2];
  const float* lin_w   = (const float*)d_in[3];
  const float* lin_b   = (const float*)d_in[4];
  const float* msg_w1  = (const float*)d_in[5];
  const float* msg_b1  = (const float*)d_in[6];
  const float* msg_w2  = (const float*)d_in[7];
  const float* msg_b2  = (const float*)d_in[8];
  const float* upd_w1  = (const float*)d_in[9];
  const float* upd_b1  = (const float*)d_in[10];
  const float* upd_w2  = (const float*)d_in[11];
  const float* upd_b2  = (const float*)d_in[12];
  const float* head_w1 = (const float*)d_in[13];
  const float* head_b1 = (const float*)d_in[14];
  const float* head_w2 = (const float*)d_in[15];
  const float* head_b2 = (const float*)d_in[16];

  int N = in_sizes[0] / 16;
  int E = in_sizes[1] / 2;
  const int* src = ei;
  const int* dst = ei + E;

  float* ws = (float*)d_ws;
  size_t NH = (size_t)N * 128;
  size_t Nr = ((size_t)N + 4) & ~(size_t)3;
  size_t Er = ((size_t)E + 3) & ~(size_t)3;
  size_t off = 0;
  float*  h    = ws + off; off += NH;
  float*  agg  = ws + off; off += NH;
  float4* eas  = (float4*)(ws + off); off += 4 * Er;
  float*  invf = ws + off; off += Nr;
  ushort* wtb  = (ushort*)(ws + off); off += (size_t)21 * 16384 / 2;
  ushort* wlin = (ushort*)(ws + off); off += 4096 / 2;
  ushort* hwb  = (ushort*)(ws + off); off += NH / 2;
  int*    cnti = (int*)(ws + off); off += Nr;
  int*    tmpc = (int*)(ws + off); off += Nr;
  int*    rowp = (int*)(ws + off); off += Nr;
  int*    srcs = (int*)(ws + off); off += Er;
  int*    dsts = (int*)(ws + off); off += Er;
  int*    bsum = (int*)(ws + off); off += 256;
  float*  out  = (float*)d_out;

  WPtrs wp;
  for (int l = 0; l < 4; ++l) {
    wp.src[l * 5 + 0] = msg_w1 + (size_t)l * 132 * 128;
    wp.src[l * 5 + 1] = msg_w2 + (size_t)l * 128 * 128;
    wp.src[l * 5 + 2] = upd_w1 + (size_t)l * 256 * 128;
    wp.src[l * 5 + 3] = upd_w1 + (size_t)l * 256 * 128 + 128 * 128;
    wp.src[l * 5 + 4] = upd_w2 + (size_t)l * 128 * 128;
  }
  wp.src[20] = head_w1;
  wp.src[21] = lin_w;

  int ngrid = (N + 63) / 64;
  int fgrid = (N + 127) / 128;
  int egrid = (E + 255) / 256;
  int nscan = (N + 255) / 256;   // 196 <= 256 partials

  hipMemsetAsync(cnti, 0, Nr * 4, stream);
  hipMemsetAsync(tmpc, 0, Nr * 4, stream);
  wconv_kernel<<<dim3(64, 22), 256, 0, stream>>>(wp, wtb, wlin);
  count_int_kernel<<<(E + 255) / 256, 256, 0, stream>>>(dst, cnti, E);
  scan_block_sum<<<nscan, 256, 0, stream>>>(cnti, bsum, N);
  scan_partials<<<1, 256, 0, stream>>>(bsum, nscan);
  scan_final<<<nscan, 256, 0, stream>>>(cnti, bsum, rowp, invf, N);
  scatter_kernel<<<(E + 255) / 256, 256, 0, stream>>>(src, dst, (const float4*)ea,
                                                      rowp, tmpc, srcs, dsts, eas, E);
  lin_hw_kernel<<<ngrid, 256, 0, stream>>>(x, wlin, lin_b, wtb, msg_b1, h, hwb, N);

  for (int l = 0; l < 4; ++l) {
    const ushort* mw2t  = wtb + (size_t)(l * 5 + 1) * 16384;
    const ushort* wu1at = wtb + (size_t)(l * 5 + 2) * 16384;
    const ushort* wu1bt = wtb + (size_t)(l * 5 + 3) * 16384;
    const ushort* wu2t  = wtb + (size_t)(l * 5 + 4) * 16384;
    const float*  wea   = msg_w1 + (size_t)l * 132 * 128 + 128 * 128;
    int last = (l == 3);
    const ushort* Wn = last ? (wtb + (size_t)20 * 16384)
                            : (wtb + (size_t)((l + 1) * 5 + 0) * 16384);
    const float* bn = last ? head_b1 : (msg_b1 + (l + 1) * 128);

    hipMemsetAsync(agg, 0, NH * sizeof(float), stream);
    edge_kernel_v7<<<egrid, 512, 0, stream>>>(hwb, eas, srcs, dsts, mw2t, wea,
                                              msg_b2 + l * 128, agg, E);
    fused_update<<<fgrid, 512, 0, stream>>>(h, agg, invf, wu1at, wu1bt, wu2t,
                                            upd_b1 + l * 128, upd_b2 + l * 128,
                                            Wn, bn, h, last ? nullptr : hwb,
                                            head_w2, head_b2, out, N, last);
  }
}

// Round 11
// 624.740 us; speedup vs baseline: 3.0467x; 1.0378x over previous
//
#include <hip/hip_runtime.h>

// MeshGNN bf16-MFMA v10. N=50000, E=600000, H=128, L=4.
// R10 lessons: (a) 512-thr edge block did NOT raise occupancy (35% vs 36%)
// and ran 17% slower than the 256-thr twin -> edge reverts to 256 thr.
// (b) 512-thr fused_update is a real win -> kept.
// R11 change: Wea staged as float4 WeaT[128] -> m1-build does 1 ds_read_b128
// per element instead of 4 scalar ds_read_b32 (4x fewer LDS ops, broadcast).

typedef __bf16 bf16x8 __attribute__((ext_vector_type(8)));
typedef float f32x4 __attribute__((ext_vector_type(4)));

__device__ inline ushort f2bf(float f) {
  unsigned u = __builtin_bit_cast(unsigned, f);
  unsigned r = (u + 0x7fff + ((u >> 16) & 1)) >> 16;
  return (ushort)r;
}
__device__ inline float bf2f(ushort h) {
  unsigned u = ((unsigned)h) << 16;
  return __builtin_bit_cast(float, u);
}

// stage bf16 weight [128n][128k] -> LDS [128][136]
template <int NT>
__device__ inline void stage_w(ushort* Ws, const ushort* __restrict__ Wt, int t) {
#pragma unroll
  for (int i = t; i < 2048; i += NT) {
    int r = i >> 4, c = i & 15;
    *(uint4*)&Ws[r * 136 + c * 8] = *(const uint4*)&Wt[r * 128 + c * 8];
  }
}
// acc += A(rows wave*16..+15 in LDS, stride 136) x W(128x128 in LDS)
__device__ inline void mfma_4ks(f32x4* acc, const ushort* A, const ushort* Ws,
                                int wave, int lane) {
  int cl = lane & 15, kq = (lane >> 4) * 8;
  int arow = (wave * 16 + cl) * 136;
#pragma unroll
  for (int ks = 0; ks < 4; ++ks) {
    bf16x8 af = *(const bf16x8*)&A[arow + ks * 32 + kq];
#pragma unroll
    for (int ct = 0; ct < 8; ++ct) {
      bf16x8 bf = *(const bf16x8*)&Ws[(ct * 16 + cl) * 136 + ks * 32 + kq];
      acc[ct] = __builtin_amdgcn_mfma_f32_16x16x32_bf16(af, bf, acc[ct], 0, 0, 0);
    }
  }
}
// acc += A(frags in regs) x W(LDS)
__device__ inline void mfma_regA(f32x4* acc, const bf16x8* af, const ushort* Ws,
                                 int lane) {
  int cl = lane & 15, kq = (lane >> 4) * 8;
#pragma unroll
  for (int ks = 0; ks < 4; ++ks) {
#pragma unroll
    for (int ct = 0; ct < 8; ++ct) {
      bf16x8 bf = *(const bf16x8*)&Ws[(ct * 16 + cl) * 136 + ks * 32 + kq];
      acc[ct] = __builtin_amdgcn_mfma_f32_16x16x32_bf16(af[ks], bf, acc[ct], 0, 0, 0);
    }
  }
}

// ---------------------------------------------------------------------------
// preprocessing: counting sort of edges by dst
__global__ __launch_bounds__(256) void count_int_kernel(const int* __restrict__ dst,
                                                        int* __restrict__ cnti, int E) {
  int e = blockIdx.x * 256 + threadIdx.x;
  if (e < E) atomicAdd(&cnti[dst[e]], 1);
}

// 3-stage multi-block exclusive scan of cnti -> rowptr (+ invf)
__global__ __launch_bounds__(256) void scan_block_sum(const int* __restrict__ cnti,
                                                      int* __restrict__ bsum, int N) {
  int i = blockIdx.x * 256 + threadIdx.x;
  int v = (i < N) ? cnti[i] : 0;
#pragma unroll
  for (int o = 1; o < 64; o <<= 1) v += __shfl_xor(v, o);
  __shared__ int wsum[4];
  if ((threadIdx.x & 63) == 0) wsum[threadIdx.x >> 6] = v;
  __syncthreads();
  if (threadIdx.x == 0) bsum[blockIdx.x] = wsum[0] + wsum[1] + wsum[2] + wsum[3];
}
__global__ __launch_bounds__(256) void scan_partials(int* __restrict__ bsum, int nb) {
  __shared__ int s[256];
  int t = threadIdx.x;
  int v = (t < nb) ? bsum[t] : 0;
  s[t] = v;
  __syncthreads();
  for (int o = 1; o < 256; o <<= 1) {
    int u = (t >= o) ? s[t - o] : 0;
    __syncthreads();
    s[t] += u;
    __syncthreads();
  }
  if (t < nb) bsum[t] = s[t] - v;   // exclusive
}
__global__ __launch_bounds__(256) void scan_final(const int* __restrict__ cnti,
                                                  const int* __restrict__ bsum,
                                                  int* __restrict__ rowptr,
                                                  float* __restrict__ invf, int N) {
  __shared__ int s[256];
  int i = blockIdx.x * 256 + threadIdx.x;
  int t = threadIdx.x;
  int v = (i < N) ? cnti[i] : 0;
  s[t] = v;
  __syncthreads();
  for (int o = 1; o < 256; o <<= 1) {
    int u = (t >= o) ? s[t - o] : 0;
    __syncthreads();
    s[t] += u;
    __syncthreads();
  }
  if (i < N) {
    rowptr[i] = bsum[blockIdx.x] + s[t] - v;
    invf[i] = 1.f / (float)max(v, 1);
  }
}

__global__ __launch_bounds__(256) void scatter_kernel(
    const int* __restrict__ src, const int* __restrict__ dst,
    const float4* __restrict__ ea, const int* __restrict__ rowptr,
    int* __restrict__ tmpc, int* __restrict__ srcs, int* __restrict__ dsts,
    float4* __restrict__ eas, int E) {
  int e = blockIdx.x * 256 + threadIdx.x;
  if (e >= E) return;
  int d = dst[e];
  int r = atomicAdd(&tmpc[d], 1);
  int p = rowptr[d] + r;
  srcs[p] = src[e];
  dsts[p] = d;
  eas[p] = ea[e];
}

// ---------------------------------------------------------------------------
// Weight convert+transpose: Wt[n][k] = bf16(W[k][n]). m==21: lin [128][32] K-pad.
struct WPtrs { const float* src[22]; };
__global__ __launch_bounds__(256) void wconv_kernel(WPtrs p, ushort* __restrict__ wtb,
                                                    ushort* __restrict__ wlin) {
  int m = blockIdx.y;
  int idx = blockIdx.x * 256 + threadIdx.x;
  if (m == 21) {
    if (idx >= 4096) return;
    int n = idx >> 5, k = idx & 31;
    wlin[idx] = (k < 16) ? f2bf(p.src[21][k * 128 + n]) : (ushort)0;
  } else {
    int n = idx >> 7, k = idx & 127;
    wtb[(size_t)m * 16384 + idx] = f2bf(p.src[m][k * 128 + n]);
  }
}

// ---------------------------------------------------------------------------
// lin_hw: h = relu(x@Win+b) ; hwb = bf16(h@Mw1_0 + mb1_0)
__global__ __launch_bounds__(256) void lin_hw_kernel(
    const float* __restrict__ x, const ushort* __restrict__ wlin,
    const float* __restrict__ lb, const ushort* __restrict__ mw1t,
    const float* __restrict__ mb1, float* __restrict__ h,
    ushort* __restrict__ hwb, int N) {
  __shared__ char smem[69632] __attribute__((aligned(16)));
  ushort* xb  = (ushort*)smem;            // [64*32]
  ushort* wsl = (ushort*)(smem + 4096);   // [128*32]
  ushort* As1 = (ushort*)(smem + 12288);  // [64*136]
  ushort* Ws  = (ushort*)(smem + 34816);  // [128*136]
  int t = threadIdx.x, lane = t & 63, wave = t >> 6;
  int m0 = blockIdx.x * 64;
  int cl = lane & 15, kq = (lane >> 4) * 8;

  for (int i = t; i < 2048; i += 256) {
    int row = i >> 5, c = i & 31;
    int m = m0 + row;
    xb[i] = (c < 16 && m < N) ? f2bf(x[(size_t)m * 16 + c]) : (ushort)0;
  }
  for (int i = t; i < 4096 / 8; i += 256)
    *(uint4*)&wsl[i * 8] = *(const uint4*)&wlin[i * 8];
  stage_w<256>(Ws, mw1t, t);
  __syncthreads();

  f32x4 acc[8];
#pragma unroll
  for (int i = 0; i < 8; ++i)
#pragma unroll
    for (int j = 0; j < 4; ++j) acc[i][j] = 0.f;
  {
    bf16x8 af = *(const bf16x8*)&xb[(wave * 16 + cl) * 32 + kq];
#pragma unroll
    for (int ct = 0; ct < 8; ++ct) {
      bf16x8 bf = *(const bf16x8*)&wsl[(ct * 16 + cl) * 32 + kq];
      acc[ct] = __builtin_amdgcn_mfma_f32_16x16x32_bf16(af, bf, acc[ct], 0, 0, 0);
    }
  }
#pragma unroll
  for (int reg = 0; reg < 4; ++reg) {
    int row = wave * 16 + (lane >> 4) * 4 + reg;
    int m = m0 + row;
#pragma unroll
    for (int ct = 0; ct < 8; ++ct) {
      int col = ct * 16 + cl;
      float v = fmaxf(acc[ct][reg] + lb[col], 0.f);
      if (m < N) h[(size_t)m * 128 + col] = v;
      As1[row * 136 + col] = f2bf(v);
    }
  }
  __syncthreads();
  f32x4 acc2[8];
#pragma unroll
  for (int i = 0; i < 8; ++i)
#pragma unroll
    for (int j = 0; j < 4; ++j) acc2[i][j] = 0.f;
  mfma_4ks(acc2, As1, Ws, wave, lane);
#pragma unroll
  for (int reg = 0; reg < 4; ++reg) {
    int m = m0 + wave * 16 + (lane >> 4) * 4 + reg;
    if (m >= N) continue;
#pragma unroll
    for (int ct = 0; ct < 8; ++ct) {
      int col = ct * 16 + cl;
      hwb[(size_t)m * 128 + col] = f2bf(acc2[ct][reg] + mb1[col]);
    }
  }
}

// ---------------------------------------------------------------------------
// edge kernel v8: 256 threads, 128 sorted edges/tile (R8 shape, proven);
// Wea in float4 WeaT[128] layout (1 ds_read_b128/elem instead of 4 b32).
__global__ __launch_bounds__(256, 4) void edge_kernel_v8(
    const ushort* __restrict__ hw, const float4* __restrict__ eas,
    const int* __restrict__ srcs, const int* __restrict__ dsts,
    const ushort* __restrict__ W2t, const float* __restrict__ Wea,
    const float* __restrict__ b2, float* __restrict__ agg, int E) {
  __shared__ ushort Ws[128 * 136];   // 34816
  __shared__ float4 WeaT[128];       // WeaT[k] = {Wea[0][k],..,Wea[3][k]}
  __shared__ float b2s[128];
  __shared__ int dss[130];           // [0]=prev-tile, [1..128]=tile, [129]=next
  int t = threadIdx.x, lane = t & 63, wave = t >> 6;
  int cl = lane & 15, g = lane >> 4;
  int p0 = blockIdx.x * 128;
  int base = wave * 32;

  // per-lane gather: lane (cl,g) owns edges base+cl and base+cl+16, k-quarter g
  int e0 = p0 + base + cl, e1 = e0 + 16;
  bool v0 = e0 < E, v1 = e1 < E;
  int s0 = v0 ? srcs[e0] : 0, s1 = v1 ? srcs[e1] : 0;
  float4 ea0 = v0 ? eas[e0] : make_float4(0.f, 0.f, 0.f, 0.f);
  float4 ea1 = v1 ? eas[e1] : make_float4(0.f, 0.f, 0.f, 0.f);
  uint4 hv0[4], hv1[4];
  {
    const ushort* h0 = hw + (size_t)s0 * 128 + g * 8;
    const ushort* h1 = hw + (size_t)s1 * 128 + g * 8;
#pragma unroll
    for (int ks = 0; ks < 4; ++ks) {
      hv0[ks] = *(const uint4*)&h0[ks * 32];
      hv1[ks] = *(const uint4*)&h1[ks * 32];
    }
  }

  // cooperative staging
  stage_w<256>(Ws, W2t, t);
  if (t < 128) {
    WeaT[t] = make_float4(Wea[t], Wea[128 + t], Wea[256 + t], Wea[384 + t]);
    b2s[t] = b2[t];
    dss[1 + t] = (p0 + t < E) ? dsts[p0 + t] : -1;
  }
  if (t == 0) dss[0] = (p0 > 0) ? dsts[p0 - 1] : -2;
  if (t == 1) dss[129] = (p0 + 128 < E) ? dsts[p0 + 128] : -3;
  __syncthreads();

  // build A fragments: m1 = relu(hw_src + ea@Wea), rank-4 in fp32
  bf16x8 af0[4], af1[4];
#pragma unroll
  for (int ks = 0; ks < 4; ++ks) {
    union { ushort u16[8]; bf16x8 v; } o0, o1;
    const ushort* q0 = (const ushort*)&hv0[ks];
    const ushort* q1 = (const ushort*)&hv1[ks];
#pragma unroll
    for (int j = 0; j < 8; ++j) {
      int k = ks * 32 + g * 8 + j;
      float4 w = WeaT[k];
      float f0 = (v0 ? bf2f(q0[j]) : 0.f) + ea0.x * w.x + ea0.y * w.y + ea0.z * w.z + ea0.w * w.w;
      float f1 = (v1 ? bf2f(q1[j]) : 0.f) + ea1.x * w.x + ea1.y * w.y + ea1.z * w.z + ea1.w * w.w;
      o0.u16[j] = f2bf(fmaxf(f0, 0.f));
      o1.u16[j] = f2bf(fmaxf(f1, 0.f));
    }
    af0[ks] = o0.v; af1[ks] = o1.v;
  }

  // MFMA
  f32x4 acc0[8], acc1[8];
#pragma unroll
  for (int i = 0; i < 8; ++i)
#pragma unroll
    for (int j = 0; j < 4; ++j) { acc0[i][j] = 0.f; acc1[i][j] = 0.f; }
#pragma unroll
  for (int ks = 0; ks < 4; ++ks) {
#pragma unroll
    for (int ct = 0; ct < 8; ++ct) {
      bf16x8 bf = *(const bf16x8*)&Ws[(ct * 16 + cl) * 136 + ks * 32 + g * 8];
      acc0[ct] = __builtin_amdgcn_mfma_f32_16x16x32_bf16(af0[ks], bf, acc0[ct], 0, 0, 0);
      acc1[ct] = __builtin_amdgcn_mfma_f32_16x16x32_bf16(af1[ks], bf, acc1[ct], 0, 0, 0);
    }
  }

  // m2 = relu(acc + b2) in place  (C layout: row=g*4+reg (+16 for acc1), col=ct*16+cl)
#pragma unroll
  for (int ct = 0; ct < 8; ++ct) {
    float bb = b2s[ct * 16 + cl];
#pragma unroll
    for (int reg = 0; reg < 4; ++reg) {
      acc0[ct][reg] = fmaxf(acc0[ct][reg] + bb, 0.f);
      acc1[ct][reg] = fmaxf(acc1[ct][reg] + bb, 0.f);
    }
  }

  // in-register segmented reduction over dst groups of this wave's 32 rows
  int rloc = lane & 31;
  int dmy = dss[1 + base + rloc];
  int dpv = dss[base + rloc];
  int dafter = dss[1 + base + 32];
  unsigned long long bm = __ballot(dmy != dpv);
  unsigned mask32 = (unsigned)bm | 1u;        // group-start bits in rows 0..31
  bool firstClosed = ((unsigned)bm & 1u) != 0;
  while (mask32) {
    int rOff = __ffs(mask32) - 1;
    unsigned rest = mask32 & (mask32 - 1);
    int eOff = rest ? (__ffs(rest) - 1) : 32;
    mask32 = rest;
    int d = __shfl(dmy, rOff);
    if (d < 0) continue;
    bool openL = (rOff == 0) && !firstClosed;
    bool openR = (eOff == 32) && (dafter == d);
    float ps[8];
#pragma unroll
    for (int ct = 0; ct < 8; ++ct) ps[ct] = 0.f;
#pragma unroll
    for (int reg = 0; reg < 4; ++reg) {
      int r0w = g * 4 + reg;
      bool in0 = (r0w >= rOff) && (r0w < eOff);
      bool in1 = (r0w + 16 >= rOff) && (r0w + 16 < eOff);
#pragma unroll
      for (int ct = 0; ct < 8; ++ct) {
        if (in0) ps[ct] += acc0[ct][reg];
        if (in1) ps[ct] += acc1[ct][reg];
      }
    }
#pragma unroll
    for (int ct = 0; ct < 8; ++ct) {
      ps[ct] += __shfl_xor(ps[ct], 16);
      ps[ct] += __shfl_xor(ps[ct], 32);
    }
    if (g == 0) {
      float* ag = &agg[(size_t)d * 128 + cl];
      if (openL || openR) {
#pragma unroll
        for (int ct = 0; ct < 8; ++ct) atomicAdd(&ag[ct * 16], ps[ct]);
      } else {
#pragma unroll
        for (int ct = 0; ct < 8; ++ct) ag[ct * 16] = ps[ct];
      }
    }
  }
}

// ---------------------------------------------------------------------------
// fused node phase per layer, 512 threads / 128 rows per block:
//   u1 = relu(h@Wu1a + (agg*inv)@Wu1b + b1)   (agg A-frags from global)
//   u  = relu(u1@Wu2 + b2 + h) -> h (skipped on last)
//   l<3 : hwb = bf16(u@Wn + bn) ; l==3: head
__global__ __launch_bounds__(512, 2) void fused_update(
    const float* __restrict__ h, const float* __restrict__ agg,
    const float* __restrict__ inv, const ushort* __restrict__ Wu1a,
    const ushort* __restrict__ Wu1b, const ushort* __restrict__ Wu2,
    const float* __restrict__ b1, const float* __restrict__ b2,
    const ushort* __restrict__ Wn, const float* __restrict__ bn,
    float* __restrict__ h_out, ushort* __restrict__ hwb,
    const float* __restrict__ hw2, const float* __restrict__ hb2,
    float* __restrict__ out, int N, int is_last) {
  __shared__ char smem[69632] __attribute__((aligned(16)));
  ushort* As1 = (ushort*)smem;             // [128*136] = 34816
  ushort* Ws  = (ushort*)(smem + 34816);   // [128*136] = 34816
  float* otile = (float*)smem;             // last: [128*130] = 66560
  float* w2s   = (float*)(smem + 66560);   // last: [384] -> 68096 <= 69632
  int t = threadIdx.x, lane = t & 63, wave = t >> 6;
  int m0 = blockIdx.x * 128;
  int cl = lane & 15, g = lane >> 4;

  // A2 (agg) fragment loads, issued first; land during GEMM1
  int m2r = m0 + wave * 16 + cl;
  bool mv = m2r < N;
  float sI = mv ? inv[m2r] : 0.f;
  float4 ga[8];
  {
    const float* gp = agg + (size_t)(mv ? m2r : 0) * 128 + g * 8;
#pragma unroll
    for (int ks = 0; ks < 4; ++ks) {
      ga[ks * 2 + 0] = *(const float4*)&gp[ks * 32];
      ga[ks * 2 + 1] = *(const float4*)&gp[ks * 32 + 4];
    }
  }

  // stage As1 = bf16(h): thread t -> row t>>2 (0..127), quarter t&3
  {
    int row = t >> 2, q = t & 3;
    int m = m0 + row;
    union { ushort u16[32]; uint4 u4[4]; } a;
    if (m < N) {
      const float* hp = h + (size_t)m * 128 + q * 32;
#pragma unroll
      for (int j = 0; j < 8; ++j) {
        float4 hv = *(const float4*)&hp[j * 4];
        a.u16[j * 4 + 0] = f2bf(hv.x); a.u16[j * 4 + 1] = f2bf(hv.y);
        a.u16[j * 4 + 2] = f2bf(hv.z); a.u16[j * 4 + 3] = f2bf(hv.w);
      }
    } else {
#pragma unroll
      for (int j = 0; j < 32; ++j) a.u16[j] = 0;
    }
#pragma unroll
    for (int j = 0; j < 4; ++j)
      *(uint4*)&As1[row * 136 + q * 32 + j * 8] = a.u4[j];
  }
  stage_w<512>(Ws, Wu1a, t);
  __syncthreads();

  f32x4 acc[8];
#pragma unroll
  for (int i = 0; i < 8; ++i)
#pragma unroll
    for (int j = 0; j < 4; ++j) acc[i][j] = 0.f;
  mfma_4ks(acc, As1, Ws, wave, lane);
  __syncthreads();
  stage_w<512>(Ws, Wu1b, t);
  // build A2 frags (loads have landed): bf16(agg * inv)
  bf16x8 af2[4];
#pragma unroll
  for (int ks = 0; ks < 4; ++ks) {
    union { ushort u16[8]; bf16x8 v; } o;
    const float* f = (const float*)&ga[ks * 2];
#pragma unroll
    for (int j = 0; j < 8; ++j) o.u16[j] = f2bf(f[j] * sI);
    af2[ks] = o.v;
  }
  __syncthreads();
  mfma_regA(acc, af2, Ws, lane);
  __syncthreads();

  // u1 -> As1 bf16 (own C rows)
#pragma unroll
  for (int reg = 0; reg < 4; ++reg) {
    int row = wave * 16 + g * 4 + reg;
#pragma unroll
    for (int ct = 0; ct < 8; ++ct) {
      int col = ct * 16 + cl;
      As1[row * 136 + col] = f2bf(fmaxf(acc[ct][reg] + b1[col], 0.f));
    }
  }
  stage_w<512>(Ws, Wu2, t);
  __syncthreads();

  f32x4 acc2[8];
#pragma unroll
  for (int i = 0; i < 8; ++i)
#pragma unroll
    for (int j = 0; j < 4; ++j) acc2[i][j] = 0.f;
  mfma_4ks(acc2, As1, Ws, wave, lane);
  __syncthreads();

  // u = relu(acc2 + b2 + h) -> h_out + As1 bf16
#pragma unroll
  for (int reg = 0; reg < 4; ++reg) {
    int row = wave * 16 + g * 4 + reg;
    int m = m0 + row;
#pragma unroll
    for (int ct = 0; ct < 8; ++ct) {
      int col = ct * 16 + cl;
      float v = acc2[ct][reg] + b2[col];
      if (m < N) v += h[(size_t)m * 128 + col];
      v = fmaxf(v, 0.f);
      if (!is_last && m < N) h_out[(size_t)m * 128 + col] = v;
      As1[row * 136 + col] = f2bf(v);
    }
  }
  stage_w<512>(Ws, Wn, t);
  __syncthreads();

  f32x4 acc3[8];
#pragma unroll
  for (int i = 0; i < 8; ++i)
#pragma unroll
    for (int j = 0; j < 4; ++j) acc3[i][j] = 0.f;
  mfma_4ks(acc3, As1, Ws, wave, lane);

  if (!is_last) {
#pragma unroll
    for (int reg = 0; reg < 4; ++reg) {
      int m = m0 + wave * 16 + g * 4 + reg;
      if (m >= N) continue;
#pragma unroll
      for (int ct = 0; ct < 8; ++ct) {
        int col = ct * 16 + cl;
        hwb[(size_t)m * 128 + col] = f2bf(acc3[ct][reg] + bn[col]);
      }
    }
  } else {
    __syncthreads();
#pragma unroll
    for (int reg = 0; reg < 4; ++reg) {
      int row = wave * 16 + g * 4 + reg;
#pragma unroll
      for (int ct = 0; ct < 8; ++ct) {
        int col = ct * 16 + cl;
        otile[row * 130 + col] = fmaxf(acc3[ct][reg] + bn[col], 0.f);
      }
    }
    for (int i = t; i < 384; i += 512) w2s[i] = hw2[i];
    __syncthreads();
    if (t < 384) {
      int row = t / 3, c = t % 3;
      int m = m0 + row;
      if (m < N) {
        float s = hb2[c];
#pragma unroll 16
        for (int k = 0; k < 128; ++k) s += otile[row * 130 + k] * w2s[k * 3 + c];
        out[(size_t)m * 3 + c] = fmaxf(s, 0.f);
      }
    }
  }
}

// ---------------------------------------------------------------------------
extern "C" void kernel_launch(void* const* d_in, const int* in_sizes, int n_in,
                              void* d_out, int out_size, void* d_ws, size_t ws_size,
                              hipStream_t stream) {
  const float* x       = (const float*)d_in[0];
  const int*   ei      = (const int*)  d_in[1];
  const float* ea      = (const float*)d_in[2];
  const float* lin_w   = (const float*)d_in[3];
  const float* lin_b   = (const float*)d_in[4];
  const float* msg_w1  = (const float*)d_in[5];
  const float* msg_b1  = (const float*)d_in[6];
  const float* msg_w2  = (const float*)d_in[7];
  const float* msg_b2  = (const float*)d_in[8];
  const float* upd_w1  = (const float*)d_in[9];
  const float* upd_b1  = (const float*)d_in[10];
  const float* upd_w2  = (const float*)d_in[11];
  const float* upd_b2  = (const float*)d_in[12];
  const float* head_w1 = (const float*)d_in[13];
  const float* head_b1 = (const float*)d_in[14];
  const float* head_w2 = (const float*)d_in[15];
  const float* head_b2 = (const float*)d_in[16];

  int N = in_sizes[0] / 16;
  int E = in_sizes[1] / 2;
  const int* src = ei;
  const int* dst = ei + E;

  float* ws = (float*)d_ws;
  size_t NH = (size_t)N * 128;
  size_t Nr = ((size_t)N + 4) & ~(size_t)3;
  size_t Er = ((size_t)E + 3) & ~(size_t)3;
  size_t off = 0;
  float*  h    = ws + off; off += NH;
  float*  agg  = ws + off; off += NH;
  float4* eas  = (float4*)(ws + off); off += 4 * Er;
  float*  invf = ws + off; off += Nr;
  ushort* wtb  = (ushort*)(ws + off); off += (size_t)21 * 16384 / 2;
  ushort* wlin = (ushort*)(ws + off); off += 4096 / 2;
  ushort* hwb  = (ushort*)(ws + off); off += NH / 2;
  int*    cnti = (int*)(ws + off); off += Nr;
  int*    tmpc = (int*)(ws + off); off += Nr;
  int*    rowp = (int*)(ws + off); off += Nr;
  int*    srcs = (int*)(ws + off); off += Er;
  int*    dsts = (int*)(ws + off); off += Er;
  int*    bsum = (int*)(ws + off); off += 256;
  float*  out  = (float*)d_out;

  WPtrs wp;
  for (int l = 0; l < 4; ++l) {
    wp.src[l * 5 + 0] = msg_w1 + (size_t)l * 132 * 128;
    wp.src[l * 5 + 1] = msg_w2 + (size_t)l * 128 * 128;
    wp.src[l * 5 + 2] = upd_w1 + (size_t)l * 256 * 128;
    wp.src[l * 5 + 3] = upd_w1 + (size_t)l * 256 * 128 + 128 * 128;
    wp.src[l * 5 + 4] = upd_w2 + (size_t)l * 128 * 128;
  }
  wp.src[20] = head_w1;
  wp.src[21] = lin_w;

  int ngrid = (N + 63) / 64;
  int fgrid = (N + 127) / 128;
  int egrid = (E + 127) / 128;
  int nscan = (N + 255) / 256;   // 196 <= 256 partials

  hipMemsetAsync(cnti, 0, Nr * 4, stream);
  hipMemsetAsync(tmpc, 0, Nr * 4, stream);
  wconv_kernel<<<dim3(64, 22), 256, 0, stream>>>(wp, wtb, wlin);
  count_int_kernel<<<(E + 255) / 256, 256, 0, stream>>>(dst, cnti, E);
  scan_block_sum<<<nscan, 256, 0, stream>>>(cnti, bsum, N);
  scan_partials<<<1, 256, 0, stream>>>(bsum, nscan);
  scan_final<<<nscan, 256, 0, stream>>>(cnti, bsum, rowp, invf, N);
  scatter_kernel<<<(E + 255) / 256, 256, 0, stream>>>(src, dst, (const float4*)ea,
                                                      rowp, tmpc, srcs, dsts, eas, E);
  lin_hw_kernel<<<ngrid, 256, 0, stream>>>(x, wlin, lin_b, wtb, msg_b1, h, hwb, N);

  for (int l = 0; l < 4; ++l) {
    const ushort* mw2t  = wtb + (size_t)(l * 5 + 1) * 16384;
    const ushort* wu1at = wtb + (size_t)(l * 5 + 2) * 16384;
    const ushort* wu1bt = wtb + (size_t)(l * 5 + 3) * 16384;
    const ushort* wu2t  = wtb + (size_t)(l * 5 + 4) * 16384;
    const float*  wea   = msg_w1 + (size_t)l * 132 * 128 + 128 * 128;
    int last = (l == 3);
    const ushort* Wn = last ? (wtb + (size_t)20 * 16384)
                            : (wtb + (size_t)((l + 1) * 5 + 0) * 16384);
    const float* bn = last ? head_b1 : (msg_b1 + (l + 1) * 128);

    hipMemsetAsync(agg, 0, NH * sizeof(float), stream);
    edge_kernel_v8<<<egrid, 256, 0, stream>>>(hwb, eas, srcs, dsts, mw2t, wea,
                                              msg_b2 + l * 128, agg, E);
    fused_update<<<fgrid, 512, 0, stream>>>(h, agg, invf, wu1at, wu1bt, wu2t,
                                            upd_b1 + l * 128, upd_b2 + l * 128,
                                            Wn, bn, h, last ? nullptr : hwb,
                                            head_w2, head_b2, out, N, last);
  }
}

// Round 13
// 598.417 us; speedup vs baseline: 3.1807x; 1.0440x over previous
//
#include <hip/hip_runtime.h>

// MeshGNN f16-MFMA v12. N=50000, E=600000, H=128, L=4.
// R13 fix: __builtin_amdgcn_cvt_pkrtz returns __fp16-vector, not _Float16-
// vector (distinct types to clang) -> receive as fp16x2 and bit_cast.
// Otherwise identical to R12: f16 GEMM inputs everywhere, packed v_pk_fma_f16
// m1-build, v_cvt_pkrtz staging, mfma_f32_16x16x32_f16. Structure = R11
// winner (256-thr edge in-reg pipeline, 512-thr fused, multi-block scan).

typedef _Float16 f16x8 __attribute__((ext_vector_type(8)));
typedef _Float16 f16x2 __attribute__((ext_vector_type(2)));
typedef __fp16  fp16x2 __attribute__((ext_vector_type(2)));
typedef float f32x4 __attribute__((ext_vector_type(4)));

__device__ inline uint pk2(float a, float b) {          // 2x f32 -> packed f16
  fp16x2 h = __builtin_amdgcn_cvt_pkrtz(a, b);
  return __builtin_bit_cast(uint, h);
}
__device__ inline ushort f2h(float f) {                 // f32 -> f16 (1 inst)
  fp16x2 h = __builtin_amdgcn_cvt_pkrtz(f, 0.f);
  return (ushort)__builtin_bit_cast(uint, h);
}
__device__ inline f16x2 bch(uint u) { return __builtin_bit_cast(f16x2, u); }

// stage f16 weight [128n][128k] -> LDS [128][136]
template <int NT>
__device__ inline void stage_w(ushort* Ws, const ushort* __restrict__ Wt, int t) {
#pragma unroll
  for (int i = t; i < 2048; i += NT) {
    int r = i >> 4, c = i & 15;
    *(uint4*)&Ws[r * 136 + c * 8] = *(const uint4*)&Wt[r * 128 + c * 8];
  }
}
// acc += A(rows wave*16..+15 in LDS, stride 136) x W(128x128 in LDS), f16
__device__ inline void mfma_4ks(f32x4* acc, const ushort* A, const ushort* Ws,
                                int wave, int lane) {
  int cl = lane & 15, kq = (lane >> 4) * 8;
  int arow = (wave * 16 + cl) * 136;
#pragma unroll
  for (int ks = 0; ks < 4; ++ks) {
    f16x8 af = *(const f16x8*)&A[arow + ks * 32 + kq];
#pragma unroll
    for (int ct = 0; ct < 8; ++ct) {
      f16x8 bf = *(const f16x8*)&Ws[(ct * 16 + cl) * 136 + ks * 32 + kq];
      acc[ct] = __builtin_amdgcn_mfma_f32_16x16x32_f16(af, bf, acc[ct], 0, 0, 0);
    }
  }
}
// acc += A(frags in regs) x W(LDS)
__device__ inline void mfma_regA(f32x4* acc, const f16x8* af, const ushort* Ws,
                                 int lane) {
  int cl = lane & 15, kq = (lane >> 4) * 8;
#pragma unroll
  for (int ks = 0; ks < 4; ++ks) {
#pragma unroll
    for (int ct = 0; ct < 8; ++ct) {
      f16x8 bf = *(const f16x8*)&Ws[(ct * 16 + cl) * 136 + ks * 32 + kq];
      acc[ct] = __builtin_amdgcn_mfma_f32_16x16x32_f16(af[ks], bf, acc[ct], 0, 0, 0);
    }
  }
}

// ---------------------------------------------------------------------------
// preprocessing: counting sort of edges by dst
__global__ __launch_bounds__(256) void count_int_kernel(const int* __restrict__ dst,
                                                        int* __restrict__ cnti, int E) {
  int e = blockIdx.x * 256 + threadIdx.x;
  if (e < E) atomicAdd(&cnti[dst[e]], 1);
}

// 3-stage multi-block exclusive scan of cnti -> rowptr (+ invf)
__global__ __launch_bounds__(256) void scan_block_sum(const int* __restrict__ cnti,
                                                      int* __restrict__ bsum, int N) {
  int i = blockIdx.x * 256 + threadIdx.x;
  int v = (i < N) ? cnti[i] : 0;
#pragma unroll
  for (int o = 1; o < 64; o <<= 1) v += __shfl_xor(v, o);
  __shared__ int wsum[4];
  if ((threadIdx.x & 63) == 0) wsum[threadIdx.x >> 6] = v;
  __syncthreads();
  if (threadIdx.x == 0) bsum[blockIdx.x] = wsum[0] + wsum[1] + wsum[2] + wsum[3];
}
__global__ __launch_bounds__(256) void scan_partials(int* __restrict__ bsum, int nb) {
  __shared__ int s[256];
  int t = threadIdx.x;
  int v = (t < nb) ? bsum[t] : 0;
  s[t] = v;
  __syncthreads();
  for (int o = 1; o < 256; o <<= 1) {
    int u = (t >= o) ? s[t - o] : 0;
    __syncthreads();
    s[t] += u;
    __syncthreads();
  }
  if (t < nb) bsum[t] = s[t] - v;   // exclusive
}
__global__ __launch_bounds__(256) void scan_final(const int* __restrict__ cnti,
                                                  const int* __restrict__ bsum,
                                                  int* __restrict__ rowptr,
                                                  float* __restrict__ invf, int N) {
  __shared__ int s[256];
  int i = blockIdx.x * 256 + threadIdx.x;
  int t = threadIdx.x;
  int v = (i < N) ? cnti[i] : 0;
  s[t] = v;
  __syncthreads();
  for (int o = 1; o < 256; o <<= 1) {
    int u = (t >= o) ? s[t - o] : 0;
    __syncthreads();
    s[t] += u;
    __syncthreads();
  }
  if (i < N) {
    rowptr[i] = bsum[blockIdx.x] + s[t] - v;
    invf[i] = 1.f / (float)max(v, 1);
  }
}

__global__ __launch_bounds__(256) void scatter_kernel(
    const int* __restrict__ src, const int* __restrict__ dst,
    const float4* __restrict__ ea, const int* __restrict__ rowptr,
    int* __restrict__ tmpc, int* __restrict__ srcs, int* __restrict__ dsts,
    float4* __restrict__ eas, int E) {
  int e = blockIdx.x * 256 + threadIdx.x;
  if (e >= E) return;
  int d = dst[e];
  int r = atomicAdd(&tmpc[d], 1);
  int p = rowptr[d] + r;
  srcs[p] = src[e];
  dsts[p] = d;
  eas[p] = ea[e];
}

// ---------------------------------------------------------------------------
// Weight convert+transpose: Wt[n][k] = f16(W[k][n]). m==21: lin [128][32] K-pad.
struct WPtrs { const float* src[22]; };
__global__ __launch_bounds__(256) void wconv_kernel(WPtrs p, ushort* __restrict__ wtb,
                                                    ushort* __restrict__ wlin) {
  int m = blockIdx.y;
  int idx = blockIdx.x * 256 + threadIdx.x;
  if (m == 21) {
    if (idx >= 4096) return;
    int n = idx >> 5, k = idx & 31;
    wlin[idx] = (k < 16) ? f2h(p.src[21][k * 128 + n]) : (ushort)0;
  } else {
    int n = idx >> 7, k = idx & 127;
    wtb[(size_t)m * 16384 + idx] = f2h(p.src[m][k * 128 + n]);
  }
}

// ---------------------------------------------------------------------------
// lin_hw: h = relu(x@Win+b) ; hwb = f16(h@Mw1_0 + mb1_0)
__global__ __launch_bounds__(256) void lin_hw_kernel(
    const float* __restrict__ x, const ushort* __restrict__ wlin,
    const float* __restrict__ lb, const ushort* __restrict__ mw1t,
    const float* __restrict__ mb1, float* __restrict__ h,
    ushort* __restrict__ hwb, int N) {
  __shared__ char smem[69632] __attribute__((aligned(16)));
  ushort* xb  = (ushort*)smem;            // [64*32]
  ushort* wsl = (ushort*)(smem + 4096);   // [128*32]
  ushort* As1 = (ushort*)(smem + 12288);  // [64*136]
  ushort* Ws  = (ushort*)(smem + 34816);  // [128*136]
  int t = threadIdx.x, lane = t & 63, wave = t >> 6;
  int m0 = blockIdx.x * 64;
  int cl = lane & 15, kq = (lane >> 4) * 8;

  for (int i = t; i < 2048; i += 256) {
    int row = i >> 5, c = i & 31;
    int m = m0 + row;
    xb[i] = (c < 16 && m < N) ? f2h(x[(size_t)m * 16 + c]) : (ushort)0;
  }
  for (int i = t; i < 4096 / 8; i += 256)
    *(uint4*)&wsl[i * 8] = *(const uint4*)&wlin[i * 8];
  stage_w<256>(Ws, mw1t, t);
  __syncthreads();

  f32x4 acc[8];
#pragma unroll
  for (int i = 0; i < 8; ++i)
#pragma unroll
    for (int j = 0; j < 4; ++j) acc[i][j] = 0.f;
  {
    f16x8 af = *(const f16x8*)&xb[(wave * 16 + cl) * 32 + kq];
#pragma unroll
    for (int ct = 0; ct < 8; ++ct) {
      f16x8 bf = *(const f16x8*)&wsl[(ct * 16 + cl) * 32 + kq];
      acc[ct] = __builtin_amdgcn_mfma_f32_16x16x32_f16(af, bf, acc[ct], 0, 0, 0);
    }
  }
#pragma unroll
  for (int reg = 0; reg < 4; ++reg) {
    int row = wave * 16 + (lane >> 4) * 4 + reg;
    int m = m0 + row;
#pragma unroll
    for (int ct = 0; ct < 8; ++ct) {
      int col = ct * 16 + cl;
      float v = fmaxf(acc[ct][reg] + lb[col], 0.f);
      if (m < N) h[(size_t)m * 128 + col] = v;
      As1[row * 136 + col] = f2h(v);
    }
  }
  __syncthreads();
  f32x4 acc2[8];
#pragma unroll
  for (int i = 0; i < 8; ++i)
#pragma unroll
    for (int j = 0; j < 4; ++j) acc2[i][j] = 0.f;
  mfma_4ks(acc2, As1, Ws, wave, lane);
#pragma unroll
  for (int reg = 0; reg < 4; ++reg) {
    int m = m0 + wave * 16 + (lane >> 4) * 4 + reg;
    if (m >= N) continue;
#pragma unroll
    for (int ct = 0; ct < 8; ++ct) {
      int col = ct * 16 + cl;
      hwb[(size_t)m * 128 + col] = f2h(acc2[ct][reg] + mb1[col]);
    }
  }
}

// ---------------------------------------------------------------------------
// edge kernel v9: 256 threads, 128 sorted edges/tile; f16 packed m1-build;
// A-frags in regs; in-register segmented reduction (raw sums; fused scales).
__global__ __launch_bounds__(256, 4) void edge_kernel_v9(
    const ushort* __restrict__ hw, const float4* __restrict__ eas,
    const int* __restrict__ srcs, const int* __restrict__ dsts,
    const ushort* __restrict__ W2t, const float* __restrict__ Wea,
    const float* __restrict__ b2, float* __restrict__ agg, int E) {
  __shared__ ushort Ws[128 * 136];   // 34816
  __shared__ uint weaH[64][4];       // weaH[k2][c] = half2{Wea[c][2k2],Wea[c][2k2+1]}
  __shared__ float b2s[128];
  __shared__ int dss[130];           // [0]=prev-tile, [1..128]=tile, [129]=next
  int t = threadIdx.x, lane = t & 63, wave = t >> 6;
  int cl = lane & 15, g = lane >> 4;
  int p0 = blockIdx.x * 128;
  int base = wave * 32;

  // per-lane gather: lane (cl,g) owns edges base+cl and base+cl+16, k-quarter g
  int e0 = p0 + base + cl, e1 = e0 + 16;
  bool v0 = e0 < E, v1 = e1 < E;
  int s0 = v0 ? srcs[e0] : 0, s1 = v1 ? srcs[e1] : 0;
  float4 ea0 = v0 ? eas[e0] : make_float4(0.f, 0.f, 0.f, 0.f);
  float4 ea1 = v1 ? eas[e1] : make_float4(0.f, 0.f, 0.f, 0.f);
  uint4 hv0[4], hv1[4];
  {
    const ushort* h0 = hw + (size_t)s0 * 128 + g * 8;
    const ushort* h1 = hw + (size_t)s1 * 128 + g * 8;
#pragma unroll
    for (int ks = 0; ks < 4; ++ks) {
      hv0[ks] = v0 ? *(const uint4*)&h0[ks * 32] : make_uint4(0, 0, 0, 0);
      hv1[ks] = v1 ? *(const uint4*)&h1[ks * 32] : make_uint4(0, 0, 0, 0);
    }
  }

  // cooperative staging
  stage_w<256>(Ws, W2t, t);
  if (t < 64) {
    weaH[t][0] = pk2(Wea[2 * t], Wea[2 * t + 1]);
    weaH[t][1] = pk2(Wea[128 + 2 * t], Wea[128 + 2 * t + 1]);
    weaH[t][2] = pk2(Wea[256 + 2 * t], Wea[256 + 2 * t + 1]);
    weaH[t][3] = pk2(Wea[384 + 2 * t], Wea[384 + 2 * t + 1]);
  }
  if (t < 128) {
    b2s[t] = b2[t];
    dss[1 + t] = (p0 + t < E) ? dsts[p0 + t] : -1;
  }
  if (t == 0) dss[0] = (p0 > 0) ? dsts[p0 - 1] : -2;
  if (t == 1) dss[129] = (p0 + 128 < E) ? dsts[p0 + 128] : -3;
  __syncthreads();

  // ea broadcasts as half2
  uint e0b[4] = {pk2(ea0.x, ea0.x), pk2(ea0.y, ea0.y), pk2(ea0.z, ea0.z), pk2(ea0.w, ea0.w)};
  uint e1b[4] = {pk2(ea1.x, ea1.x), pk2(ea1.y, ea1.y), pk2(ea1.z, ea1.z), pk2(ea1.w, ea1.w)};

  // build A fragments: m1 = relu(hw_src + ea@Wea), packed f16
  f16x8 af0[4], af1[4];
  f16x2 z2 = {};
#pragma unroll
  for (int ks = 0; ks < 4; ++ks) {
    union { uint u32[4]; f16x8 v; } o0, o1;
    const uint* q0 = (const uint*)&hv0[ks];
    const uint* q1 = (const uint*)&hv1[ks];
    int k2b = ks * 16 + g * 4;
#pragma unroll
    for (int p = 0; p < 4; ++p) {
      uint4 w4 = *(const uint4*)&weaH[k2b + p][0];
      f16x2 m0h = bch(q0[p]);
      f16x2 m1h = bch(q1[p]);
      m0h += bch(e0b[0]) * bch(w4.x); m1h += bch(e1b[0]) * bch(w4.x);
      m0h += bch(e0b[1]) * bch(w4.y); m1h += bch(e1b[1]) * bch(w4.y);
      m0h += bch(e0b[2]) * bch(w4.z); m1h += bch(e1b[2]) * bch(w4.z);
      m0h += bch(e0b[3]) * bch(w4.w); m1h += bch(e1b[3]) * bch(w4.w);
      o0.u32[p] = __builtin_bit_cast(uint, __builtin_elementwise_max(m0h, z2));
      o1.u32[p] = __builtin_bit_cast(uint, __builtin_elementwise_max(m1h, z2));
    }
    af0[ks] = o0.v; af1[ks] = o1.v;
  }

  // MFMA
  f32x4 acc0[8], acc1[8];
#pragma unroll
  for (int i = 0; i < 8; ++i)
#pragma unroll
    for (int j = 0; j < 4; ++j) { acc0[i][j] = 0.f; acc1[i][j] = 0.f; }
#pragma unroll
  for (int ks = 0; ks < 4; ++ks) {
#pragma unroll
    for (int ct = 0; ct < 8; ++ct) {
      f16x8 bf = *(const f16x8*)&Ws[(ct * 16 + cl) * 136 + ks * 32 + g * 8];
      acc0[ct] = __builtin_amdgcn_mfma_f32_16x16x32_f16(af0[ks], bf, acc0[ct], 0, 0, 0);
      acc1[ct] = __builtin_amdgcn_mfma_f32_16x16x32_f16(af1[ks], bf, acc1[ct], 0, 0, 0);
    }
  }

  // m2 = relu(acc + b2) in place  (C layout: row=g*4+reg (+16 for acc1), col=ct*16+cl)
#pragma unroll
  for (int ct = 0; ct < 8; ++ct) {
    float bb = b2s[ct * 16 + cl];
#pragma unroll
    for (int reg = 0; reg < 4; ++reg) {
      acc0[ct][reg] = fmaxf(acc0[ct][reg] + bb, 0.f);
      acc1[ct][reg] = fmaxf(acc1[ct][reg] + bb, 0.f);
    }
  }

  // in-register segmented reduction over dst groups of this wave's 32 rows
  int rloc = lane & 31;
  int dmy = dss[1 + base + rloc];
  int dpv = dss[base + rloc];
  int dafter = dss[1 + base + 32];
  unsigned long long bm = __ballot(dmy != dpv);
  unsigned mask32 = (unsigned)bm | 1u;        // group-start bits in rows 0..31
  bool firstClosed = ((unsigned)bm & 1u) != 0;
  while (mask32) {
    int rOff = __ffs(mask32) - 1;
    unsigned rest = mask32 & (mask32 - 1);
    int eOff = rest ? (__ffs(rest) - 1) : 32;
    mask32 = rest;
    int d = __shfl(dmy, rOff);
    if (d < 0) continue;
    bool openL = (rOff == 0) && !firstClosed;
    bool openR = (eOff == 32) && (dafter == d);
    float ps[8];
#pragma unroll
    for (int ct = 0; ct < 8; ++ct) ps[ct] = 0.f;
#pragma unroll
    for (int reg = 0; reg < 4; ++reg) {
      int r0w = g * 4 + reg;
      bool in0 = (r0w >= rOff) && (r0w < eOff);
      bool in1 = (r0w + 16 >= rOff) && (r0w + 16 < eOff);
#pragma unroll
      for (int ct = 0; ct < 8; ++ct) {
        if (in0) ps[ct] += acc0[ct][reg];
        if (in1) ps[ct] += acc1[ct][reg];
      }
    }
#pragma unroll
    for (int ct = 0; ct < 8; ++ct) {
      ps[ct] += __shfl_xor(ps[ct], 16);
      ps[ct] += __shfl_xor(ps[ct], 32);
    }
    if (g == 0) {
      float* ag = &agg[(size_t)d * 128 + cl];
      if (openL || openR) {
#pragma unroll
        for (int ct = 0; ct < 8; ++ct) atomicAdd(&ag[ct * 16], ps[ct]);
      } else {
#pragma unroll
        for (int ct = 0; ct < 8; ++ct) ag[ct * 16] = ps[ct];
      }
    }
  }
}

// ---------------------------------------------------------------------------
// fused node phase per layer, 512 threads / 128 rows per block:
//   u1 = relu(h@Wu1a + (agg*inv)@Wu1b + b1)   (agg A-frags from global)
//   u  = relu(u1@Wu2 + b2 + h) -> h (skipped on last)
//   l<3 : hwb = f16(u@Wn + bn) ; l==3: head
__global__ __launch_bounds__(512, 2) void fused_update(
    const float* __restrict__ h, const float* __restrict__ agg,
    const float* __restrict__ inv, const ushort* __restrict__ Wu1a,
    const ushort* __restrict__ Wu1b, const ushort* __restrict__ Wu2,
    const float* __restrict__ b1, const float* __restrict__ b2,
    const ushort* __restrict__ Wn, const float* __restrict__ bn,
    float* __restrict__ h_out, ushort* __restrict__ hwb,
    const float* __restrict__ hw2, const float* __restrict__ hb2,
    float* __restrict__ out, int N, int is_last) {
  __shared__ char smem[69632] __attribute__((aligned(16)));
  ushort* As1 = (ushort*)smem;             // [128*136] = 34816
  ushort* Ws  = (ushort*)(smem + 34816);   // [128*136] = 34816
  float* otile = (float*)smem;             // last: [128*130] = 66560
  float* w2s   = (float*)(smem + 66560);   // last: [384] -> 68096 <= 69632
  int t = threadIdx.x, lane = t & 63, wave = t >> 6;
  int m0 = blockIdx.x * 128;
  int cl = lane & 15, g = lane >> 4;

  // A2 (agg) fragment loads, issued first; land during GEMM1
  int m2r = m0 + wave * 16 + cl;
  bool mv = m2r < N;
  float sI = mv ? inv[m2r] : 0.f;
  float4 ga[8];
  {
    const float* gp = agg + (size_t)(mv ? m2r : 0) * 128 + g * 8;
#pragma unroll
    for (int ks = 0; ks < 4; ++ks) {
      ga[ks * 2 + 0] = *(const float4*)&gp[ks * 32];
      ga[ks * 2 + 1] = *(const float4*)&gp[ks * 32 + 4];
    }
  }

  // stage As1 = f16(h): thread t -> row t>>2 (0..127), quarter t&3
  {
    int row = t >> 2, q = t & 3;
    int m = m0 + row;
    union { uint u32[16]; uint4 u4[4]; } a;
    if (m < N) {
      const float* hp = h + (size_t)m * 128 + q * 32;
#pragma unroll
      for (int j = 0; j < 8; ++j) {
        float4 hv = *(const float4*)&hp[j * 4];
        a.u32[j * 2 + 0] = pk2(hv.x, hv.y);
        a.u32[j * 2 + 1] = pk2(hv.z, hv.w);
      }
    } else {
#pragma unroll
      for (int j = 0; j < 16; ++j) a.u32[j] = 0;
    }
#pragma unroll
    for (int j = 0; j < 4; ++j)
      *(uint4*)&As1[row * 136 + q * 32 + j * 8] = a.u4[j];
  }
  stage_w<512>(Ws, Wu1a, t);
  __syncthreads();

  f32x4 acc[8];
#pragma unroll
  for (int i = 0; i < 8; ++i)
#pragma unroll
    for (int j = 0; j < 4; ++j) acc[i][j] = 0.f;
  mfma_4ks(acc, As1, Ws, wave, lane);
  __syncthreads();
  stage_w<512>(Ws, Wu1b, t);
  // build A2 frags (loads have landed): f16(agg * inv)
  f16x8 af2[4];
#pragma unroll
  for (int ks = 0; ks < 4; ++ks) {
    union { uint u32[4]; f16x8 v; } o;
    const float* f = (const float*)&ga[ks * 2];
#pragma unroll
    for (int j = 0; j < 4; ++j)
      o.u32[j] = pk2(f[j * 2] * sI, f[j * 2 + 1] * sI);
    af2[ks] = o.v;
  }
  __syncthreads();
  mfma_regA(acc, af2, Ws, lane);
  __syncthreads();

  // u1 -> As1 f16 (own C rows)
#pragma unroll
  for (int reg = 0; reg < 4; ++reg) {
    int row = wave * 16 + g * 4 + reg;
#pragma unroll
    for (int ct = 0; ct < 8; ++ct) {
      int col = ct * 16 + cl;
      As1[row * 136 + col] = f2h(fmaxf(acc[ct][reg] + b1[col], 0.f));
    }
  }
  stage_w<512>(Ws, Wu2, t);
  __syncthreads();

  f32x4 acc2[8];
#pragma unroll
  for (int i = 0; i < 8; ++i)
#pragma unroll
    for (int j = 0; j < 4; ++j) acc2[i][j] = 0.f;
  mfma_4ks(acc2, As1, Ws, wave, lane);
  __syncthreads();

  // u = relu(acc2 + b2 + h) -> h_out + As1 f16
#pragma unroll
  for (int reg = 0; reg < 4; ++reg) {
    int row = wave * 16 + g * 4 + reg;
    int m = m0 + row;
#pragma unroll
    for (int ct = 0; ct < 8; ++ct) {
      int col = ct * 16 + cl;
      float v = acc2[ct][reg] + b2[col];
      if (m < N) v += h[(size_t)m * 128 + col];
      v = fmaxf(v, 0.f);
      if (!is_last && m < N) h_out[(size_t)m * 128 + col] = v;
      As1[row * 136 + col] = f2h(v);
    }
  }
  stage_w<512>(Ws, Wn, t);
  __syncthreads();

  f32x4 acc3[8];
#pragma unroll
  for (int i = 0; i < 8; ++i)
#pragma unroll
    for (int j = 0; j < 4; ++j) acc3[i][j] = 0.f;
  mfma_4ks(acc3, As1, Ws, wave, lane);

  if (!is_last) {
#pragma unroll
    for (int reg = 0; reg < 4; ++reg) {
      int m = m0 + wave * 16 + g * 4 + reg;
      if (m >= N) continue;
#pragma unroll
      for (int ct = 0; ct < 8; ++ct) {
        int col = ct * 16 + cl;
        hwb[(size_t)m * 128 + col] = f2h(acc3[ct][reg] + bn[col]);
      }
    }
  } else {
    __syncthreads();
#pragma unroll
    for (int reg = 0; reg < 4; ++reg) {
      int row = wave * 16 + g * 4 + reg;
#pragma unroll
      for (int ct = 0; ct < 8; ++ct) {
        int col = ct * 16 + cl;
        otile[row * 130 + col] = fmaxf(acc3[ct][reg] + bn[col], 0.f);
      }
    }
    for (int i = t; i < 384; i += 512) w2s[i] = hw2[i];
    __syncthreads();
    if (t < 384) {
      int row = t / 3, c = t % 3;
      int m = m0 + row;
      if (m < N) {
        float s = hb2[c];
#pragma unroll 16
        for (int k = 0; k < 128; ++k) s += otile[row * 130 + k] * w2s[k * 3 + c];
        out[(size_t)m * 3 + c] = fmaxf(s, 0.f);
      }
    }
  }
}

// ---------------------------------------------------------------------------
extern "C" void kernel_launch(void* const* d_in, const int* in_sizes, int n_in,
                              void* d_out, int out_size, void* d_ws, size_t ws_size,
                              hipStream_t stream) {
  const float* x       = (const float*)d_in[0];
  const int*   ei      = (const int*)  d_in[1];
  const float* ea      = (const float*)d_in[2];
  const float* lin_w   = (const float*)d_in[3];
  const float* lin_b   = (const float*)d_in[4];
  const float* msg_w1  = (const float*)d_in[5];
  const float* msg_b1  = (const float*)d_in[6];
  const float* msg_w2  = (const float*)d_in[7];
  const float* msg_b2  = (const float*)d_in[8];
  const float* upd_w1  = (const float*)d_in[9];
  const float* upd_b1  = (const float*)d_in[10];
  const float* upd_w2  = (const float*)d_in[11];
  const float* upd_b2  = (const float*)d_in[12];
  const float* head_w1 = (const float*)d_in[13];
  const float* head_b1 = (const float*)d_in[14];
  const float* head_w2 = (const float*)d_in[15];
  const float* head_b2 = (const float*)d_in[16];

  int N = in_sizes[0] / 16;
  int E = in_sizes[1] / 2;
  const int* src = ei;
  const int* dst = ei + E;

  float* ws = (float*)d_ws;
  size_t NH = (size_t)N * 128;
  size_t Nr = ((size_t)N + 4) & ~(size_t)3;
  size_t Er = ((size_t)E + 3) & ~(size_t)3;
  size_t off = 0;
  float*  h    = ws + off; off += NH;
  float*  agg  = ws + off; off += NH;
  float4* eas  = (float4*)(ws + off); off += 4 * Er;
  float*  invf = ws + off; off += Nr;
  ushort* wtb  = (ushort*)(ws + off); off += (size_t)21 * 16384 / 2;
  ushort* wlin = (ushort*)(ws + off); off += 4096 / 2;
  ushort* hwb  = (ushort*)(ws + off); off += NH / 2;
  int*    cnti = (int*)(ws + off); off += Nr;
  int*    tmpc = (int*)(ws + off); off += Nr;
  int*    rowp = (int*)(ws + off); off += Nr;
  int*    srcs = (int*)(ws + off); off += Er;
  int*    dsts = (int*)(ws + off); off += Er;
  int*    bsum = (int*)(ws + off); off += 256;
  float*  out  = (float*)d_out;

  WPtrs wp;
  for (int l = 0; l < 4; ++l) {
    wp.src[l * 5 + 0] = msg_w1 + (size_t)l * 132 * 128;
    wp.src[l * 5 + 1] = msg_w2 + (size_t)l * 128 * 128;
    wp.src[l * 5 + 2] = upd_w1 + (size_t)l * 256 * 128;
    wp.src[l * 5 + 3] = upd_w1 + (size_t)l * 256 * 128 + 128 * 128;
    wp.src[l * 5 + 4] = upd_w2 + (size_t)l * 128 * 128;
  }
  wp.src[20] = head_w1;
  wp.src[21] = lin_w;

  int ngrid = (N + 63) / 64;
  int fgrid = (N + 127) / 128;
  int egrid = (E + 127) / 128;
  int nscan = (N + 255) / 256;   // 196 <= 256 partials

  hipMemsetAsync(cnti, 0, Nr * 4, stream);
  hipMemsetAsync(tmpc, 0, Nr * 4, stream);
  wconv_kernel<<<dim3(64, 22), 256, 0, stream>>>(wp, wtb, wlin);
  count_int_kernel<<<(E + 255) / 256, 256, 0, stream>>>(dst, cnti, E);
  scan_block_sum<<<nscan, 256, 0, stream>>>(cnti, bsum, N);
  scan_partials<<<1, 256, 0, stream>>>(bsum, nscan);
  scan_final<<<nscan, 256, 0, stream>>>(cnti, bsum, rowp, invf, N);
  scatter_kernel<<<(E + 255) / 256, 256, 0, stream>>>(src, dst, (const float4*)ea,
                                                      rowp, tmpc, srcs, dsts, eas, E);
  lin_hw_kernel<<<ngrid, 256, 0, stream>>>(x, wlin, lin_b, wtb, msg_b1, h, hwb, N);

  for (int l = 0; l < 4; ++l) {
    const ushort* mw2t  = wtb + (size_t)(l * 5 + 1) * 16384;
    const ushort* wu1at = wtb + (size_t)(l * 5 + 2) * 16384;
    const ushort* wu1bt = wtb + (size_t)(l * 5 + 3) * 16384;
    const ushort* wu2t  = wtb + (size_t)(l * 5 + 4) * 16384;
    const float*  wea   = msg_w1 + (size_t)l * 132 * 128 + 128 * 128;
    int last = (l == 3);
    const ushort* Wn = last ? (wtb + (size_t)20 * 16384)
                            : (wtb + (size_t)((l + 1) * 5 + 0) * 16384);
    const float* bn = last ? head_b1 : (msg_b1 + (l + 1) * 128);

    hipMemsetAsync(agg, 0, NH * sizeof(float), stream);
    edge_kernel_v9<<<egrid, 256, 0, stream>>>(hwb, eas, srcs, dsts, mw2t, wea,
                                              msg_b2 + l * 128, agg, E);
    fused_update<<<fgrid, 512, 0, stream>>>(h, agg, invf, wu1at, wu1bt, wu2t,
                                            upd_b1 + l * 128, upd_b2 + l * 128,
                                            Wn, bn, h, last ? nullptr : hwb,
                                            head_w2, head_b2, out, N, last);
  }
}